// Round 1
// 1452.414 us; speedup vs baseline: 1.3022x; 1.3022x over previous
//
#include <hip/hip_runtime.h>

typedef __attribute__((ext_vector_type(4))) float f4;
typedef __attribute__((ext_vector_type(8))) __bf16 bf16x8;
typedef __attribute__((ext_vector_type(4))) __bf16 bf16x4;
typedef __attribute__((ext_vector_type(4))) unsigned short u16x4;

// dims: E=4 B=8 L=768 C=1024 H=768 Q=144 NH=12 HD=64 O=4096 NL=2 MLP=3072
// stages: Sq={64,48,32} qoff={0,64,112}; T={320,304,288}; loff={0,256,512}

// async global->LDS, 16B per lane, wave-uniform LDS base + lane*16
#define GLD16(gp, lp)                                                        \
  __builtin_amdgcn_global_load_lds(                                          \
      (__attribute__((address_space(1))) void*)(gp),                         \
      (__attribute__((address_space(3))) void*)(lp), 16, 0, 0)

// ---------------------------------------------------------------- gate
__global__ __launch_bounds__(256) void gate_kernel(
    const float* __restrict__ x, const float* __restrict__ lnw,
    const float* __restrict__ lnb, const float* __restrict__ gwm,
    const float* __restrict__ gb, float* __restrict__ out) {
  const long r = blockIdx.x;
  const int tid = threadIdx.x;
  f4 v = *(const f4*)(x + r * 1024 + tid * 4);
  float s1 = v[0] + v[1] + v[2] + v[3];
  float s2 = v[0]*v[0] + v[1]*v[1] + v[2]*v[2] + v[3]*v[3];
#pragma unroll
  for (int off = 32; off; off >>= 1) { s1 += __shfl_down(s1, off); s2 += __shfl_down(s2, off); }
  __shared__ float red[8];
  const int wv = tid >> 6;
  if ((tid & 63) == 0) { red[wv*2] = s1; red[wv*2+1] = s2; }
  __syncthreads();
  const float sum = red[0]+red[2]+red[4]+red[6];
  const float sq  = red[1]+red[3]+red[5]+red[7];
  const float mean = sum * (1.f/1024.f);
  const float var  = sq * (1.f/1024.f) - mean*mean;
  const float rstd = rsqrtf(var + 1e-5f);
  f4 lw = *(const f4*)(lnw + tid*4);
  f4 lb = *(const f4*)(lnb + tid*4);
  f4 acc = {0.f,0.f,0.f,0.f};
#pragma unroll
  for (int i = 0; i < 4; i++) {
    float n = (v[i]-mean)*rstd*lw[i] + lb[i];
    f4 g = *(const f4*)(gwm + (long)(tid*4+i)*4);
    acc += n * g;
  }
#pragma unroll
  for (int off = 32; off; off >>= 1) {
    acc[0] += __shfl_down(acc[0], off); acc[1] += __shfl_down(acc[1], off);
    acc[2] += __shfl_down(acc[2], off); acc[3] += __shfl_down(acc[3], off);
  }
  __shared__ f4 red4[4];
  if ((tid & 63) == 0) red4[wv] = acc;
  __syncthreads();
  if (tid == 0) {
    f4 tot = red4[0] + red4[1] + red4[2] + red4[3];
    float lg[4], mx = -1e30f;
#pragma unroll
    for (int e = 0; e < 4; e++) {
      float tv = tot[e] + gb[e];
      tv = fminf(15.f, fmaxf(-15.f, tv));
      lg[e] = tv; mx = fmaxf(mx, tv);
    }
    float den = 0.f;
#pragma unroll
    for (int e = 0; e < 4; e++) { float ev = __expf(lg[e]-mx); lg[e] = ev; den += ev; }
    const float inv = 1.f/den;
    f4 o;
#pragma unroll
    for (int e = 0; e < 4; e++) o[e] = lg[e]*inv;
    *(f4*)(out + r*4) = o;
  }
}

// ------------------------------------------------- weight transpose+cvt
__global__ __launch_bounds__(256) void transpose_cvt(
    const float* __restrict__ src, __bf16* __restrict__ dst,
    int srcLd, int K, long srcZ, long dstZ) {
  __shared__ float tile[32][33];
  const long so = (long)blockIdx.z * srcZ;
  const long dxo = (long)blockIdx.z * dstZ;
  const int n0 = blockIdx.x * 32, k0 = blockIdx.y * 32;
  const int tx = threadIdx.x & 31, ty = threadIdx.x >> 5;
#pragma unroll
  for (int i = ty; i < 32; i += 8)
    tile[i][tx] = src[so + (long)(k0 + i) * srcLd + n0 + tx];
  __syncthreads();
#pragma unroll
  for (int i = ty; i < 32; i += 8)
    dst[dxo + (long)(n0 + i) * K + k0 + tx] = (__bf16)tile[tx][i];
}

// ---------------------------------------------------------------- fp32 -> bf16 cvt
__global__ __launch_bounds__(256) void cvt_bf16_kernel(
    const float* __restrict__ in, __bf16* __restrict__ out) {
  const long i = ((long)blockIdx.x * 256 + threadIdx.x) * 4;
  f4 v = *(const f4*)(in + i);
  bf16x4 o;
  o[0] = (__bf16)v[0]; o[1] = (__bf16)v[1]; o[2] = (__bf16)v[2]; o[3] = (__bf16)v[3];
  *(bf16x4*)(out + i) = o;
}

// ---------------------------------------------------------------- zero f32
__global__ __launch_bounds__(256) void zero_f32_kernel(float* __restrict__ p) {
  const long i = ((long)blockIdx.x * 256 + threadIdx.x) * 4;
  *(f4*)(p + i) = (f4){0.f, 0.f, 0.f, 0.f};
}

// ---------------------------------------------------------------- LN (t rows, fp32 -> bf16)
__global__ __launch_bounds__(256) void ln_rows_kernel(
    const float* __restrict__ in, __bf16* __restrict__ out,
    const float* __restrict__ w, const float* __restrict__ b) {
  const long r = blockIdx.x;
  const int e = (int)(r / 1152);
  const float* src = in + r * 768;
  const int tid = threadIdx.x;
  float v0 = src[tid], v1 = src[tid+256], v2 = src[tid+512];
  float s1 = v0+v1+v2, s2 = v0*v0+v1*v1+v2*v2;
#pragma unroll
  for (int off = 32; off; off >>= 1) { s1 += __shfl_down(s1, off); s2 += __shfl_down(s2, off); }
  __shared__ float red[8];
  const int wv = tid >> 6;
  if ((tid & 63) == 0) { red[wv*2] = s1; red[wv*2+1] = s2; }
  __syncthreads();
  const float sum = red[0]+red[2]+red[4]+red[6];
  const float sq  = red[1]+red[3]+red[5]+red[7];
  const float mean = sum * (1.f/768.f);
  const float var  = sq * (1.f/768.f) - mean*mean;
  const float rstd = rsqrtf(var + 1e-5f);
  const float* wp = w + (long)e * 1536;
  const float* bp = b + (long)e * 1536;
  __bf16* dst = out + r * 768;
  dst[tid]     = (__bf16)((v0-mean)*rstd*wp[tid]     + bp[tid]);
  dst[tid+256] = (__bf16)((v1-mean)*rstd*wp[tid+256] + bp[tid+256]);
  dst[tid+512] = (__bf16)((v2-mean)*rstd*wp[tid+512] + bp[tid+512]);
}

// ---------------------------------------------------------------- LN (kv gather, one stage)
__global__ __launch_bounds__(256) void ln_kv_kernel(
    const __bf16* __restrict__ h, const float* __restrict__ query,
    __bf16* __restrict__ out, const float* __restrict__ w, const float* __restrict__ b,
    int T, int Sq, int qoffG, int loff) {
  const long r = blockIdx.x;
  const int e = (int)(r / (8*T));
  const int rem = (int)(r % (8*T));
  const int bb = rem / T;
  const int p = rem % T;
  const int tid = threadIdx.x;
  float v0, v1, v2;
  if (p < Sq) {
    const float* src = query + ((long)e * 144 + qoffG + p) * 768;
    v0 = src[tid]; v1 = src[tid+256]; v2 = src[tid+512];
  } else {
    const __bf16* src = h + (((long)e * 8 + bb) * 768 + loff + (p - Sq)) * 768;
    v0 = (float)src[tid]; v1 = (float)src[tid+256]; v2 = (float)src[tid+512];
  }
  float s1 = v0+v1+v2, s2 = v0*v0+v1*v1+v2*v2;
#pragma unroll
  for (int off = 32; off; off >>= 1) { s1 += __shfl_down(s1, off); s2 += __shfl_down(s2, off); }
  __shared__ float red[8];
  const int wv = tid >> 6;
  if ((tid & 63) == 0) { red[wv*2] = s1; red[wv*2+1] = s2; }
  __syncthreads();
  const float sum = red[0]+red[2]+red[4]+red[6];
  const float sq  = red[1]+red[3]+red[5]+red[7];
  const float mean = sum * (1.f/768.f);
  const float var  = sq * (1.f/768.f) - mean*mean;
  const float rstd = rsqrtf(var + 1e-5f);
  const float* wp = w + (long)e * 1536;
  const float* bp2 = b + (long)e * 1536;
  __bf16* dst = out + r * 768;
  dst[tid]     = (__bf16)((v0-mean)*rstd*wp[tid]     + bp2[tid]);
  dst[tid+256] = (__bf16)((v1-mean)*rstd*wp[tid+256] + bp2[tid+256]);
  dst[tid+512] = (__bf16)((v2-mean)*rstd*wp[tid+512] + bp2[tid+512]);
}

// ---------------------------------------------------------------- t init
__global__ __launch_bounds__(256) void init_t_kernel(
    const float* __restrict__ query, float* __restrict__ t) {
  const long i4 = ((long)blockIdx.x * 256 + threadIdx.x) * 4;
  const int e = (int)(i4 / 884736);
  const int rq = (int)(i4 % 110592);
  *(f4*)(t + i4) = *(const f4*)(query + (long)e * 110592 + rq);
}

// ---------------------------------------------------------------- MFMA GEMM
// A is ALWAYS bf16 [M][K] row-major; Bt bf16 [N][K] row-major.
// MODE 0: C=acc+bias           | 1: gelu(acc+bias)
// MODE 4: C = vec[m*4+z]*acc + bias (row gate)
// MODE 5: out-proj fused: z=(e*2+c); atomicAdd(C[(z&1)*2048 + ...], acc+bias)
// MODE 6: split-K MODE2: z=(half*4+e); atomicAdd(C, vec[n]*(acc + half0?bias:0))
// Staging: global_load_lds dwordx4 into linear LDS [2][128][32], double-buffered,
// one barrier per 32-wide K-step (m97/T3-minimum structure).
struct GemmP {
  const __bf16* A; long sAz; int lda;
  const __bf16* Bt; long sBz; int ldb;
  void* C; long sCz; int ldc;
  const float* bias; long sBiasZ;
  const float* vec; long sVecZ;
  int K;
};

template<int MODE, bool C_BF16>
__global__ __launch_bounds__(256) void gemm128(GemmP p) {
  __shared__ __bf16 As[2][128][32];
  __shared__ __bf16 Bs[2][128][32];
  const int z = blockIdx.z;
  int e = z, koff = 0, KK = p.K;
  if (MODE == 5) { e = z >> 1; }
  if (MODE == 6) { e = z & 3; KK = p.K >> 1; koff = (z >> 2) * KK; }

  const __bf16* Ab = p.A + (long)e * p.sAz + koff;
  const __bf16* Bb = p.Bt + (long)(MODE == 5 ? z : e) * p.sBz + koff;
  const float* bias = p.bias + (long)(MODE == 5 ? z : e) * p.sBiasZ;
  const float* vec = (MODE == 4 || MODE == 6) ? (p.vec + (long)e * p.sVecZ) : nullptr;

  const int m0 = blockIdx.x * 128, n0 = blockIdx.y * 128;
  const int tid = threadIdx.x;
  const int w = tid >> 6, lane = tid & 63;
  const int lr = lane & 15, qd = lane >> 4;
  const int wm = (w & 1) * 64, wn = (w >> 1) * 64;

  // staging map: wave w owns rows [w*32, w*32+32); lane l -> row w*32+(l>>2),
  // col (l&3)*8 bf16 (16B). LDS dest = wave-uniform base + lane*16 (linear).
  const int sr = w * 32 + (lane >> 2);
  const int sc = (lane & 3) * 8;
  const int lda = p.lda, ldb = p.ldb;
  const __bf16* gA = Ab + (long)(m0 + sr) * lda + sc;
  const __bf16* gB = Bb + (long)(n0 + sr) * ldb + sc;

  f4 acc[4][4];
#pragma unroll
  for (int i = 0; i < 4; i++)
#pragma unroll
    for (int j = 0; j < 4; j++) acc[i][j] = (f4){0.f, 0.f, 0.f, 0.f};

  const int nk = KK >> 5;

#define STAGE(buf, t)                                        \
  do {                                                       \
    const __bf16* a_ = gA + (long)(t) * 32;                  \
    const __bf16* b_ = gB + (long)(t) * 32;                  \
    GLD16(a_,                 &As[buf][w * 32][0]);          \
    GLD16(a_ + 16 * lda,      &As[buf][w * 32 + 16][0]);     \
    GLD16(b_,                 &Bs[buf][w * 32][0]);          \
    GLD16(b_ + 16 * ldb,      &Bs[buf][w * 32 + 16][0]);     \
  } while (0)

  STAGE(0, 0);
  __syncthreads();  // drains vmcnt -> buf0 ready for all waves
  int cur = 0;
  for (int t = 0; t < nk; ++t) {
    if (t + 1 < nk) STAGE(cur ^ 1, t + 1);  // async next-tile loads in flight
    bf16x8 af[4], bfr[4];
#pragma unroll
    for (int i = 0; i < 4; i++) af[i] = *(const bf16x8*)&As[cur][wm + i*16 + lr][qd*8];
#pragma unroll
    for (int j = 0; j < 4; j++) bfr[j] = *(const bf16x8*)&Bs[cur][wn + j*16 + lr][qd*8];
#pragma unroll
    for (int i = 0; i < 4; i++)
#pragma unroll
      for (int j = 0; j < 4; j++)
        acc[i][j] = __builtin_amdgcn_mfma_f32_16x16x32_bf16(af[i], bfr[j], acc[i][j], 0, 0, 0);
    __syncthreads();  // vmcnt(0)+lgkmcnt(0) drain: next buffer staged, reads done
    cur ^= 1;
  }
#undef STAGE

  long cOff;
  if (MODE == 5)      cOff = (long)(z & 1) * 2048;
  else if (MODE == 6) cOff = (long)e * p.sCz;
  else                cOff = (long)z * p.sCz;
  float* Cf = (float*)p.C + cOff;
  __bf16* Cb = (__bf16*)p.C + cOff;
#pragma unroll
  for (int i = 0; i < 4; i++) {
    const int rbase = m0 + wm + i*16 + qd*4;
#pragma unroll
    for (int j = 0; j < 4; j++) {
      const int col = n0 + wn + j*16 + lr;
      const float bcol = bias[col];
      f4 v = acc[i][j];
#pragma unroll
      for (int r = 0; r < 4; r++) {
        const long o = (long)(rbase + r) * p.ldc + col;
        const float xx = v[r];
        if (MODE == 0) {
          const float y = xx + bcol;
          if (C_BF16) Cb[o] = (__bf16)y; else Cf[o] = y;
        } else if (MODE == 1) {
          const float y = xx + bcol;
          const float g = 0.5f * y * (1.0f + erff(y * 0.70710678118654752f));
          if (C_BF16) Cb[o] = (__bf16)g; else Cf[o] = g;
        } else if (MODE == 4) {
          const float y = vec[(long)(rbase + r) * 4 + z] * xx + bcol;
          if (C_BF16) Cb[o] = (__bf16)y; else Cf[o] = y;
        } else if (MODE == 5) {
          unsafeAtomicAdd(&Cf[o], xx + bcol);
        } else if (MODE == 6) {
          unsafeAtomicAdd(&Cf[o], vec[col] * (xx + (koff == 0 ? bcol : 0.f)));
        }
      }
    }
  }
}

// ---------------------------------------------------------------- MFMA attention
template<int TSQ, int TT>
__global__ __launch_bounds__(256) void attn_mfma_kernel(
    const __bf16* __restrict__ qh, const __bf16* __restrict__ kvh,
    __bf16* __restrict__ att, int qoffG) {
  constexpr int MT = TSQ / 16;        // 4/3/2
  constexpr int NT = TT / 16;         // 20/19/18
  constexpr int NC = (TT + 31) / 32;  // 10/10/9
  constexpr int TC = NC * 32;         // 320/320/288
  constexpr int TPAD = 328;
  __shared__ __bf16 Plds[64 * TPAD];  // 41984 B
  __shared__ unsigned Vt32[64 * 20];  // 5120 B
  __shared__ float redf[64 * 4];      // 1024 B

  const int hh = blockIdx.x;
  const long eb = blockIdx.y;
  const int tid = threadIdx.x;
  const int w = tid >> 6, lane = tid & 63, lr = lane & 15, qd = lane >> 4;

  const __bf16* qb = qh + ((long)eb * 144 + qoffG) * 768 + hh * 64;
  const __bf16* kb = kvh + (long)eb * TT * 1536 + hh * 64;
  const __bf16* vb = kb + 768;

  bf16x8 qf[MT][2];
#pragma unroll
  for (int mt = 0; mt < MT; mt++)
#pragma unroll
    for (int kc = 0; kc < 2; kc++)
      qf[mt][kc] = *(const bf16x8*)(qb + (long)(mt*16 + lr)*768 + kc*32 + qd*8);

  f4 sacc[MT][5];
#pragma unroll
  for (int mt = 0; mt < MT; mt++)
#pragma unroll
    for (int j = 0; j < 5; j++) sacc[mt][j] = (f4){0.f,0.f,0.f,0.f};
#pragma unroll
  for (int j = 0; j < 5; j++) {
    const int jj = w + 4*j;
    if (jj < NT) {
      const int t0 = jj * 16;
      bf16x8 kf0 = *(const bf16x8*)(kb + (long)(t0 + lr)*1536 + qd*8);
      bf16x8 kf1 = *(const bf16x8*)(kb + (long)(t0 + lr)*1536 + 32 + qd*8);
#pragma unroll
      for (int mt = 0; mt < MT; mt++) {
        sacc[mt][j] = __builtin_amdgcn_mfma_f32_16x16x32_bf16(qf[mt][0], kf0, sacc[mt][j], 0,0,0);
        sacc[mt][j] = __builtin_amdgcn_mfma_f32_16x16x32_bf16(qf[mt][1], kf1, sacc[mt][j], 0,0,0);
      }
    }
  }

  float rowmax[MT][4], linv[MT][4], ps[MT][4];
#pragma unroll
  for (int mt = 0; mt < MT; mt++)
#pragma unroll
    for (int r = 0; r < 4; r++) {
      float m = -1e30f;
#pragma unroll
      for (int j = 0; j < 5; j++)
        if (w + 4*j < NT) m = fmaxf(m, sacc[mt][j][r]);
#pragma unroll
      for (int d = 1; d < 16; d <<= 1) m = fmaxf(m, __shfl_xor(m, d));
      rowmax[mt][r] = m;
    }
  if (lr == 0) {
#pragma unroll
    for (int mt = 0; mt < MT; mt++)
#pragma unroll
      for (int r = 0; r < 4; r++)
        redf[(mt*16 + qd*4 + r)*4 + w] = rowmax[mt][r];
  }
  __syncthreads();
#pragma unroll
  for (int mt = 0; mt < MT; mt++)
#pragma unroll
    for (int r = 0; r < 4; r++) {
      f4 v = *(const f4*)&redf[(mt*16 + qd*4 + r)*4];
      rowmax[mt][r] = fmaxf(fmaxf(v[0],v[1]), fmaxf(v[2],v[3])) * 0.125f;
      ps[mt][r] = 0.f;
    }

#pragma unroll
  for (int j = 0; j < 5; j++) {
    const int jj = w + 4*j;
    if (jj < NT) {
#pragma unroll
      for (int mt = 0; mt < MT; mt++)
#pragma unroll
        for (int r = 0; r < 4; r++) {
          float e = __expf(sacc[mt][j][r]*0.125f - rowmax[mt][r]);
          ps[mt][r] += e;
          Plds[(mt*16 + qd*4 + r)*TPAD + jj*16 + lr] = (__bf16)e;
        }
    }
  }
#pragma unroll
  for (int mt = 0; mt < MT; mt++)
#pragma unroll
    for (int r = 0; r < 4; r++) {
      float s = ps[mt][r];
#pragma unroll
      for (int d = 1; d < 16; d <<= 1) s += __shfl_xor(s, d);
      ps[mt][r] = s;
    }
  __syncthreads();
  if (lr == 0) {
#pragma unroll
    for (int mt = 0; mt < MT; mt++)
#pragma unroll
      for (int r = 0; r < 4; r++)
        redf[(mt*16 + qd*4 + r)*4 + w] = ps[mt][r];
  }
  if (TC > TT) {
    for (int idx = tid; idx < 64*(TC-TT); idx += 256) {
      const int rr = idx / (TC-TT), cc = idx % (TC-TT);
      Plds[rr*TPAD + TT + cc] = (__bf16)0.f;
    }
  }
  __syncthreads();
#pragma unroll
  for (int mt = 0; mt < MT; mt++)
#pragma unroll
    for (int r = 0; r < 4; r++) {
      f4 v = *(const f4*)&redf[(mt*16 + qd*4 + r)*4];
      linv[mt][r] = 1.f / (v[0]+v[1]+v[2]+v[3]);
    }

  f4 oacc[MT];
#pragma unroll
  for (int mt = 0; mt < MT; mt++) oacc[mt] = (f4){0.f,0.f,0.f,0.f};
  const int n0 = w * 16;
  for (int c = 0; c < NC; c++) {
    {
      const int tp = tid & 15, dq = tid >> 4;
      const int t0v = c*32 + tp*2;
      u16x4 v0 = (u16x4){0,0,0,0}, v1 = (u16x4){0,0,0,0};
      if (t0v < TT)     v0 = *(const u16x4*)(vb + (long)t0v*1536 + dq*4);
      if (t0v + 1 < TT) v1 = *(const u16x4*)(vb + (long)(t0v+1)*1536 + dq*4);
#pragma unroll
      for (int i = 0; i < 4; i++)
        Vt32[(dq*4 + i)*20 + tp] = ((unsigned)v1[i] << 16) | (unsigned)v0[i];
    }
    __syncthreads();
    bf16x8 vf = *(const bf16x8*)&Vt32[(n0 + lr)*20 + qd*4];
#pragma unroll
    for (int mt = 0; mt < MT; mt++) {
      bf16x8 pf = *(const bf16x8*)&Plds[(mt*16 + lr)*TPAD + c*32 + qd*8];
      oacc[mt] = __builtin_amdgcn_mfma_f32_16x16x32_bf16(pf, vf, oacc[mt], 0,0,0);
    }
    __syncthreads();
  }

  __bf16* ob = att + ((long)eb*144 + qoffG)*768 + hh*64 + n0 + lr;
#pragma unroll
  for (int mt = 0; mt < MT; mt++)
#pragma unroll
    for (int r = 0; r < 4; r++) {
      const int row = mt*16 + qd*4 + r;
      ob[(long)row * 768] = (__bf16)(oacc[mt][r] * linv[mt][r]);
    }
}

// ---------------------------------------------------------------- RMSNorm
__global__ __launch_bounds__(256) void rmsnorm_kernel(
    const float* __restrict__ in, const float* __restrict__ w,
    const float* __restrict__ g, float* __restrict__ out) {
  const long r = blockIdx.x;
  const int tid = threadIdx.x;
  const float* src = in + r*4096;
  f4 vv[4]; float s2 = 0.f;
#pragma unroll
  for (int i = 0; i < 4; i++) {
    vv[i] = *(const f4*)(src + i*1024 + tid*4);
    s2 += vv[i][0]*vv[i][0] + vv[i][1]*vv[i][1] + vv[i][2]*vv[i][2] + vv[i][3]*vv[i][3];
  }
#pragma unroll
  for (int off = 32; off; off >>= 1) s2 += __shfl_down(s2, off);
  __shared__ float red[4];
  if ((tid & 63) == 0) red[tid >> 6] = s2;
  __syncthreads();
  const float ms = (red[0]+red[1]+red[2]+red[3]) * (1.f/4096.f);
  const float scl = rsqrtf(ms + 1e-6f);
#pragma unroll
  for (int i = 0; i < 4; i++) {
    const int o = i*1024 + tid*4;
    f4 wv = *(const f4*)(w + o);
    f4 gv = *(const f4*)(g + o);
    f4 res = vv[i] * scl * wv * gv;
    *(f4*)(out + r*4096 + o) = res;
  }
}

// ================================================================ launch
extern "C" void kernel_launch(void* const* d_in, const int* in_sizes, int n_in,
                              void* d_out, int out_size, void* d_ws, size_t ws_size,
                              hipStream_t stream) {
  const float* x          = (const float*)d_in[0];
  const float* gate_ln_w  = (const float*)d_in[1];
  const float* gate_ln_b  = (const float*)d_in[2];
  const float* gate_w     = (const float*)d_in[3];
  const float* gate_b     = (const float*)d_in[4];
  const float* exp_in_w   = (const float*)d_in[5];
  const float* exp_in_b   = (const float*)d_in[6];
  const float* exp_query  = (const float*)d_in[7];
  const float* ln1_w      = (const float*)d_in[8];
  const float* ln1_b      = (const float*)d_in[9];
  const float* ln1kv_w    = (const float*)d_in[10];
  const float* ln1kv_b    = (const float*)d_in[11];
  const float* ln2_w      = (const float*)d_in[12];
  const float* ln2_b      = (const float*)d_in[13];
  const float* attn_in_w  = (const float*)d_in[14];
  const float* attn_in_b  = (const float*)d_in[15];
  const float* attn_out_w = (const float*)d_in[16];
  const float* attn_out_b = (const float*)d_in[17];
  const float* ls1        = (const float*)d_in[18];
  const float* ls2        = (const float*)d_in[19];
  const float* fc_w       = (const float*)d_in[20];
  const float* fc_b       = (const float*)d_in[21];
  const float* proj_w     = (const float*)d_in[22];
  const float* proj_b     = (const float*)d_in[23];
  const float* out_w      = (const float*)d_in[24];
  const float* out_b      = (const float*)d_in[25];
  const float* rms_w      = (const float*)d_in[26];
  const float* out_gain   = (const float*)d_in[27];
  float* out = (float*)d_out;

  // ---- workspace layout (byte offsets), total 132,218,880 B (unchanged)
  char* W = (char*)d_ws;
  float*   gw     = (float*)(W + 0);
  float*   t      = (float*)(W + 98304);
  __bf16*  qn     = (__bf16*)(W + 14254080);     // alias att; tb after last fc
  __bf16*  tb     = (__bf16*)(W + 14254080);     // t in bf16 for out-proj
  __bf16*  qh     = (__bf16*)(W + 21331968);
  __bf16*  kvn    = (__bf16*)(W + 28409856);
  __bf16*  kvh    = (__bf16*)(W + 44138496);     // alias mid, outw_t
  __bf16*  mid    = (__bf16*)(W + 44138496);
  __bf16*  outw_t = (__bf16*)(W + 44138496);     // 25.2 MB <= 31.4 MB region
  __bf16*  h      = (__bf16*)(W + 75595776);
  float*   mixed  = (float*)(W + 75595776);      // alias h (h dead by then)
  __bf16*  wbuf   = (__bf16*)(W + 113344512);    // 6.29 MB weights
  __bf16*  xb     = (__bf16*)(W + 119635968);    // x in bf16, 12.58 MB (tail)
  const size_t NEED = 132218880ull;
  if (ws_size < NEED) return;

  // ---- gating + bf16 copy of x
  cvt_bf16_kernel<<<6144, 256, 0, stream>>>(x, xb);
  gate_kernel<<<6144, 256, 0, stream>>>(x, gate_ln_w, gate_ln_b, gate_w, gate_b, gw);

  // ---- expert input proj: h[e] = gate_e * (x @ exp_in_w[e]) + bias
  transpose_cvt<<<dim3(24,32,4), 256, 0, stream>>>(exp_in_w, wbuf, 768, 1024, 786432, 786432);
  { GemmP p{ xb, 0, 1024, wbuf, 786432, 1024, h, 4718592, 768,
             exp_in_b, 768, gw, 0, 1024 };
    gemm128<4,true><<<dim3(48,6,4), 256, 0, stream>>>(p); }
  init_t_kernel<<<3456, 256, 0, stream>>>(exp_query, t);

  const int ST[3]  = {320, 304, 288};
  const int SQ[3]  = {64, 48, 32};
  const int QO[3]  = {0, 64, 112};
  const int LO[3]  = {0, 256, 512};

  for (int li = 0; li < 2; li++) {
    transpose_cvt<<<dim3(72,24,4), 256, 0, stream>>>(
        attn_in_w + (long)li*768*2304, wbuf, 2304, 768, 3538944, 1769472);
    ln_rows_kernel<<<4608, 256, 0, stream>>>(t, qn, ln1_w + li*768, ln1_b + li*768);
    { GemmP p{ qn, 884736, 768, wbuf, 1769472, 768, qh, 884736, 768,
               attn_in_b + li*2304, 4608, nullptr, 0, 768 };
      gemm128<0,true><<<dim3(9,6,4), 256, 0, stream>>>(p); }
    for (int s = 0; s < 3; s++) {
      const int T = ST[s];
      ln_kv_kernel<<<32*T, 256, 0, stream>>>(h, exp_query, kvn,
          ln1kv_w + li*768, ln1kv_b + li*768, T, SQ[s], QO[s], LO[s]);
      { GemmP p{ kvn, (long)8*T*768, 768, wbuf + 768*768, 1769472, 768,
                 kvh, (long)8*T*1536, 1536,
                 attn_in_b + li*2304 + 768, 4608, nullptr, 0, 768 };
        gemm128<0,true><<<dim3(8*T/128,12,4), 256, 0, stream>>>(p); }
      if (s == 0)
        attn_mfma_kernel<64,320><<<dim3(12,32), 256, 0, stream>>>(qh, kvh, qn, QO[s]);
      else if (s == 1)
        attn_mfma_kernel<48,304><<<dim3(12,32), 256, 0, stream>>>(qh, kvh, qn, QO[s]);
      else
        attn_mfma_kernel<32,288><<<dim3(12,32), 256, 0, stream>>>(qh, kvh, qn, QO[s]);
    }
    // attn out proj with split-K=2 (z = half*4 + e), atomic += into t
    transpose_cvt<<<dim3(24,24,4), 256, 0, stream>>>(
        attn_out_w + (long)li*589824, wbuf, 768, 768, 1179648, 589824);
    { GemmP p{ qn /*att*/, 884736, 768, wbuf, 589824, 768, t, 884736, 768,
               attn_out_b + li*768, 1536, ls1 + li*768, 1536, 768 };
      gemm128<6,false><<<dim3(9,6,8), 256, 0, stream>>>(p); }
    ln_rows_kernel<<<4608, 256, 0, stream>>>(t, qn, ln2_w + li*768, ln2_b + li*768);
    transpose_cvt<<<dim3(96,24,4), 256, 0, stream>>>(
        fc_w + (long)li*768*3072, wbuf, 3072, 768, 4718592, 2359296);
    { GemmP p{ qn, 884736, 768, wbuf, 2359296, 768, mid, 3538944, 3072,
               fc_b + li*3072, 6144, nullptr, 0, 768 };
      gemm128<1,true><<<dim3(9,24,4), 256, 0, stream>>>(p); }
    transpose_cvt<<<dim3(24,96,4), 256, 0, stream>>>(
        proj_w + (long)li*3072*768, wbuf, 768, 3072, 4718592, 2359296);
    { GemmP p{ mid, 3538944, 3072, wbuf, 2359296, 3072, t, 884736, 768,
               proj_b + li*768, 1536, ls2 + li*768, 1536, 3072 };
      gemm128<6,false><<<dim3(9,6,8), 256, 0, stream>>>(p); }
  }

  // ---- final out proj: single fused gemm over z=(e*2+c), atomic accumulate
  cvt_bf16_kernel<<<3456, 256, 0, stream>>>(t, tb);
  zero_f32_kernel<<<4608, 256, 0, stream>>>(mixed);
  transpose_cvt<<<dim3(128,24,4), 256, 0, stream>>>(out_w, outw_t, 4096, 768, 3145728, 3145728);
  { GemmP p{ tb, 884736, 768, outw_t, 1572864, 768, mixed, 0, 4096,
             out_b, 2048, nullptr, 0, 768 };
    gemm128<5,false><<<dim3(9,16,8), 256, 0, stream>>>(p); }
  rmsnorm_kernel<<<1152, 256, 0, stream>>>(mixed, rms_w, out_gain, out);
}

// Round 2
// 1416.237 us; speedup vs baseline: 1.3355x; 1.0255x over previous
//
#include <hip/hip_runtime.h>

typedef __attribute__((ext_vector_type(4))) float f4;
typedef __attribute__((ext_vector_type(8))) __bf16 bf16x8;
typedef __attribute__((ext_vector_type(4))) __bf16 bf16x4;
typedef __attribute__((ext_vector_type(4))) unsigned short u16x4;

// dims: E=4 B=8 L=768 C=1024 H=768 Q=144 NH=12 HD=64 O=4096 NL=2 MLP=3072
// stages: Sq={64,48,32} qoff={0,64,112}; T={320,304,288}; loff={0,256,512}

// async global->LDS, 16B per lane, wave-uniform LDS base + lane*16
#define GLD16(gp, lp)                                                        \
  __builtin_amdgcn_global_load_lds(                                          \
      (__attribute__((address_space(1))) void*)(gp),                         \
      (__attribute__((address_space(3))) void*)(lp), 16, 0, 0)

// ---------------------------------------------------------------- gate (+x->bf16 fused)
__global__ __launch_bounds__(256) void gate_kernel(
    const float* __restrict__ x, const float* __restrict__ lnw,
    const float* __restrict__ lnb, const float* __restrict__ gwm,
    const float* __restrict__ gb, float* __restrict__ out,
    __bf16* __restrict__ xb) {
  const long r = blockIdx.x;
  const int tid = threadIdx.x;
  f4 v = *(const f4*)(x + r * 1024 + tid * 4);
  // fused bf16 copy of x (saves a separate 25 MB re-read)
  bf16x4 xo;
  xo[0] = (__bf16)v[0]; xo[1] = (__bf16)v[1]; xo[2] = (__bf16)v[2]; xo[3] = (__bf16)v[3];
  *(bf16x4*)(xb + r * 1024 + tid * 4) = xo;
  float s1 = v[0] + v[1] + v[2] + v[3];
  float s2 = v[0]*v[0] + v[1]*v[1] + v[2]*v[2] + v[3]*v[3];
#pragma unroll
  for (int off = 32; off; off >>= 1) { s1 += __shfl_down(s1, off); s2 += __shfl_down(s2, off); }
  __shared__ float red[8];
  const int wv = tid >> 6;
  if ((tid & 63) == 0) { red[wv*2] = s1; red[wv*2+1] = s2; }
  __syncthreads();
  const float sum = red[0]+red[2]+red[4]+red[6];
  const float sq  = red[1]+red[3]+red[5]+red[7];
  const float mean = sum * (1.f/1024.f);
  const float var  = sq * (1.f/1024.f) - mean*mean;
  const float rstd = rsqrtf(var + 1e-5f);
  f4 lw = *(const f4*)(lnw + tid*4);
  f4 lb = *(const f4*)(lnb + tid*4);
  f4 acc = {0.f,0.f,0.f,0.f};
#pragma unroll
  for (int i = 0; i < 4; i++) {
    float n = (v[i]-mean)*rstd*lw[i] + lb[i];
    f4 g = *(const f4*)(gwm + (long)(tid*4+i)*4);
    acc += n * g;
  }
#pragma unroll
  for (int off = 32; off; off >>= 1) {
    acc[0] += __shfl_down(acc[0], off); acc[1] += __shfl_down(acc[1], off);
    acc[2] += __shfl_down(acc[2], off); acc[3] += __shfl_down(acc[3], off);
  }
  __shared__ f4 red4[4];
  if ((tid & 63) == 0) red4[wv] = acc;
  __syncthreads();
  if (tid == 0) {
    f4 tot = red4[0] + red4[1] + red4[2] + red4[3];
    float lg[4], mx = -1e30f;
#pragma unroll
    for (int e = 0; e < 4; e++) {
      float tv = tot[e] + gb[e];
      tv = fminf(15.f, fmaxf(-15.f, tv));
      lg[e] = tv; mx = fmaxf(mx, tv);
    }
    float den = 0.f;
#pragma unroll
    for (int e = 0; e < 4; e++) { float ev = __expf(lg[e]-mx); lg[e] = ev; den += ev; }
    const float inv = 1.f/den;
    f4 o;
#pragma unroll
    for (int e = 0; e < 4; e++) o[e] = lg[e]*inv;
    *(f4*)(out + r*4) = o;
  }
}

// ------------------------------------------------- weight transpose+cvt
// dst[dxo + n*K + k] = (bf16)src[so + k*srcLd + n]; K is dst row stride.
__global__ __launch_bounds__(256) void transpose_cvt(
    const float* __restrict__ src, __bf16* __restrict__ dst,
    int srcLd, int K, long srcZ, long dstZ) {
  __shared__ float tile[32][33];
  const long so = (long)blockIdx.z * srcZ;
  const long dxo = (long)blockIdx.z * dstZ;
  const int n0 = blockIdx.x * 32, k0 = blockIdx.y * 32;
  const int tx = threadIdx.x & 31, ty = threadIdx.x >> 5;
#pragma unroll
  for (int i = ty; i < 32; i += 8)
    tile[i][tx] = src[so + (long)(k0 + i) * srcLd + n0 + tx];
  __syncthreads();
#pragma unroll
  for (int i = ty; i < 32; i += 8)
    dst[dxo + (long)(n0 + i) * K + k0 + tx] = (__bf16)tile[tx][i];
}

// ---------------------------------------------------------------- t -> tb_cat (K-concat over experts)
// tb_cat[m][e*768+k] = (bf16)t[e][m][k]
__global__ __launch_bounds__(256) void cvt_tcat_kernel(
    const float* __restrict__ t, __bf16* __restrict__ o) {
  const long i4 = ((long)blockIdx.x * 256 + threadIdx.x) * 4;
  const int e = (int)(i4 / 884736);
  const int rem = (int)(i4 % 884736);
  const int m = rem / 768, k = rem % 768;
  f4 v = *(const f4*)(t + i4);
  bf16x4 w;
  w[0] = (__bf16)v[0]; w[1] = (__bf16)v[1]; w[2] = (__bf16)v[2]; w[3] = (__bf16)v[3];
  *(bf16x4*)(o + (long)m * 3072 + e * 768 + k) = w;
}

// ---------------------------------------------------------------- bias sum over experts
__global__ __launch_bounds__(256) void bias_sum_kernel(
    const float* __restrict__ b, float* __restrict__ o) {
  const int i = blockIdx.x * 256 + threadIdx.x;  // 4096 total
  o[i] = b[i] + b[4096 + i] + b[8192 + i] + b[12288 + i];
}

// ---------------------------------------------------------------- LN (t rows, fp32 -> bf16)
__global__ __launch_bounds__(256) void ln_rows_kernel(
    const float* __restrict__ in, __bf16* __restrict__ out,
    const float* __restrict__ w, const float* __restrict__ b) {
  const long r = blockIdx.x;
  const int e = (int)(r / 1152);
  const float* src = in + r * 768;
  const int tid = threadIdx.x;
  float v0 = src[tid], v1 = src[tid+256], v2 = src[tid+512];
  float s1 = v0+v1+v2, s2 = v0*v0+v1*v1+v2*v2;
#pragma unroll
  for (int off = 32; off; off >>= 1) { s1 += __shfl_down(s1, off); s2 += __shfl_down(s2, off); }
  __shared__ float red[8];
  const int wv = tid >> 6;
  if ((tid & 63) == 0) { red[wv*2] = s1; red[wv*2+1] = s2; }
  __syncthreads();
  const float sum = red[0]+red[2]+red[4]+red[6];
  const float sq  = red[1]+red[3]+red[5]+red[7];
  const float mean = sum * (1.f/768.f);
  const float var  = sq * (1.f/768.f) - mean*mean;
  const float rstd = rsqrtf(var + 1e-5f);
  const float* wp = w + (long)e * 1536;
  const float* bp = b + (long)e * 1536;
  __bf16* dst = out + r * 768;
  dst[tid]     = (__bf16)((v0-mean)*rstd*wp[tid]     + bp[tid]);
  dst[tid+256] = (__bf16)((v1-mean)*rstd*wp[tid+256] + bp[tid+256]);
  dst[tid+512] = (__bf16)((v2-mean)*rstd*wp[tid+512] + bp[tid+512]);
}

// ---------------------------------------------------------------- LN (kv gather, one stage)
__global__ __launch_bounds__(256) void ln_kv_kernel(
    const __bf16* __restrict__ h, const float* __restrict__ query,
    __bf16* __restrict__ out, const float* __restrict__ w, const float* __restrict__ b,
    int T, int Sq, int qoffG, int loff) {
  const long r = blockIdx.x;
  const int e = (int)(r / (8*T));
  const int rem = (int)(r % (8*T));
  const int bb = rem / T;
  const int p = rem % T;
  const int tid = threadIdx.x;
  float v0, v1, v2;
  if (p < Sq) {
    const float* src = query + ((long)e * 144 + qoffG + p) * 768;
    v0 = src[tid]; v1 = src[tid+256]; v2 = src[tid+512];
  } else {
    const __bf16* src = h + (((long)e * 8 + bb) * 768 + loff + (p - Sq)) * 768;
    v0 = (float)src[tid]; v1 = (float)src[tid+256]; v2 = (float)src[tid+512];
  }
  float s1 = v0+v1+v2, s2 = v0*v0+v1*v1+v2*v2;
#pragma unroll
  for (int off = 32; off; off >>= 1) { s1 += __shfl_down(s1, off); s2 += __shfl_down(s2, off); }
  __shared__ float red[8];
  const int wv = tid >> 6;
  if ((tid & 63) == 0) { red[wv*2] = s1; red[wv*2+1] = s2; }
  __syncthreads();
  const float sum = red[0]+red[2]+red[4]+red[6];
  const float sq  = red[1]+red[3]+red[5]+red[7];
  const float mean = sum * (1.f/768.f);
  const float var  = sq * (1.f/768.f) - mean*mean;
  const float rstd = rsqrtf(var + 1e-5f);
  const float* wp = w + (long)e * 1536;
  const float* bp2 = b + (long)e * 1536;
  __bf16* dst = out + r * 768;
  dst[tid]     = (__bf16)((v0-mean)*rstd*wp[tid]     + bp2[tid]);
  dst[tid+256] = (__bf16)((v1-mean)*rstd*wp[tid+256] + bp2[tid+256]);
  dst[tid+512] = (__bf16)((v2-mean)*rstd*wp[tid+512] + bp2[tid+512]);
}

// ---------------------------------------------------------------- t init
__global__ __launch_bounds__(256) void init_t_kernel(
    const float* __restrict__ query, float* __restrict__ t) {
  const long i4 = ((long)blockIdx.x * 256 + threadIdx.x) * 4;
  const int e = (int)(i4 / 884736);
  const int rq = (int)(i4 % 110592);
  *(f4*)(t + i4) = *(const f4*)(query + (long)e * 110592 + rq);
}

// ---------------------------------------------------------------- MFMA GEMM
// A is ALWAYS bf16 [M][K] row-major; Bt bf16 [N][K] row-major.
// MODE 0: C=acc+bias           | 1: gelu(acc+bias)
// MODE 4: C = vec[m*4+z]*acc + bias (row gate)
// MODE 6: split-K: z=(half*4+e); atomicAdd(C, vec[n]*(acc + half0?bias:0))
// Staging: global_load_lds dwordx4 into linear LDS [2][128][32], double-buffered,
// one barrier per 32-wide K-step (m97/T3-minimum structure).
struct GemmP {
  const __bf16* A; long sAz; int lda;
  const __bf16* Bt; long sBz; int ldb;
  void* C; long sCz; int ldc;
  const float* bias; long sBiasZ;
  const float* vec; long sVecZ;
  int K;
};

template<int MODE, bool C_BF16>
__global__ __launch_bounds__(256) void gemm128(GemmP p) {
  __shared__ __bf16 As[2][128][32];
  __shared__ __bf16 Bs[2][128][32];
  const int z = blockIdx.z;
  int e = z, koff = 0, KK = p.K;
  if (MODE == 6) { e = z & 3; KK = p.K >> 1; koff = (z >> 2) * KK; }

  const __bf16* Ab = p.A + (long)e * p.sAz + koff;
  const __bf16* Bb = p.Bt + (long)e * p.sBz + koff;
  const float* bias = p.bias + (long)e * p.sBiasZ;
  const float* vec = (MODE == 4 || MODE == 6) ? (p.vec + (long)e * p.sVecZ) : nullptr;

  const int m0 = blockIdx.x * 128, n0 = blockIdx.y * 128;
  const int tid = threadIdx.x;
  const int w = tid >> 6, lane = tid & 63;
  const int lr = lane & 15, qd = lane >> 4;
  const int wm = (w & 1) * 64, wn = (w >> 1) * 64;

  // staging map: wave w owns rows [w*32, w*32+32); lane l -> row w*32+(l>>2),
  // col (l&3)*8 bf16 (16B). LDS dest = wave-uniform base + lane*16 (linear).
  const int sr = w * 32 + (lane >> 2);
  const int sc = (lane & 3) * 8;
  const int lda = p.lda, ldb = p.ldb;
  const __bf16* gA = Ab + (long)(m0 + sr) * lda + sc;
  const __bf16* gB = Bb + (long)(n0 + sr) * ldb + sc;

  f4 acc[4][4];
#pragma unroll
  for (int i = 0; i < 4; i++)
#pragma unroll
    for (int j = 0; j < 4; j++) acc[i][j] = (f4){0.f, 0.f, 0.f, 0.f};

  const int nk = KK >> 5;

#define STAGE(buf, t)                                        \
  do {                                                       \
    const __bf16* a_ = gA + (long)(t) * 32;                  \
    const __bf16* b_ = gB + (long)(t) * 32;                  \
    GLD16(a_,                 &As[buf][w * 32][0]);          \
    GLD16(a_ + 16 * lda,      &As[buf][w * 32 + 16][0]);     \
    GLD16(b_,                 &Bs[buf][w * 32][0]);          \
    GLD16(b_ + 16 * ldb,      &Bs[buf][w * 32 + 16][0]);     \
  } while (0)

  STAGE(0, 0);
  __syncthreads();  // drains vmcnt -> buf0 ready for all waves
  int cur = 0;
  for (int t = 0; t < nk; ++t) {
    if (t + 1 < nk) STAGE(cur ^ 1, t + 1);  // async next-tile loads in flight
    bf16x8 af[4], bfr[4];
#pragma unroll
    for (int i = 0; i < 4; i++) af[i] = *(const bf16x8*)&As[cur][wm + i*16 + lr][qd*8];
#pragma unroll
    for (int j = 0; j < 4; j++) bfr[j] = *(const bf16x8*)&Bs[cur][wn + j*16 + lr][qd*8];
#pragma unroll
    for (int i = 0; i < 4; i++)
#pragma unroll
      for (int j = 0; j < 4; j++)
        acc[i][j] = __builtin_amdgcn_mfma_f32_16x16x32_bf16(af[i], bfr[j], acc[i][j], 0, 0, 0);
    __syncthreads();  // vmcnt(0)+lgkmcnt(0) drain: next buffer staged, reads done
    cur ^= 1;
  }
#undef STAGE

  const long cOff = (MODE == 6) ? (long)e * p.sCz : (long)z * p.sCz;
  float* Cf = (float*)p.C + cOff;
  __bf16* Cb = (__bf16*)p.C + cOff;
#pragma unroll
  for (int i = 0; i < 4; i++) {
    const int rbase = m0 + wm + i*16 + qd*4;
#pragma unroll
    for (int j = 0; j < 4; j++) {
      const int col = n0 + wn + j*16 + lr;
      const float bcol = bias[col];
      f4 v = acc[i][j];
#pragma unroll
      for (int r = 0; r < 4; r++) {
        const long o = (long)(rbase + r) * p.ldc + col;
        const float xx = v[r];
        if (MODE == 0) {
          const float y = xx + bcol;
          if (C_BF16) Cb[o] = (__bf16)y; else Cf[o] = y;
        } else if (MODE == 1) {
          const float y = xx + bcol;
          const float g = 0.5f * y * (1.0f + erff(y * 0.70710678118654752f));
          if (C_BF16) Cb[o] = (__bf16)g; else Cf[o] = g;
        } else if (MODE == 4) {
          const float y = vec[(long)(rbase + r) * 4 + z] * xx + bcol;
          if (C_BF16) Cb[o] = (__bf16)y; else Cf[o] = y;
        } else if (MODE == 6) {
          unsafeAtomicAdd(&Cf[o], vec[col] * (xx + (koff == 0 ? bcol : 0.f)));
        }
      }
    }
  }
}

// ---------------------------------------------------------------- MFMA attention
template<int TSQ, int TT>
__global__ __launch_bounds__(256) void attn_mfma_kernel(
    const __bf16* __restrict__ qh, const __bf16* __restrict__ kvh,
    __bf16* __restrict__ att, int qoffG) {
  constexpr int MT = TSQ / 16;        // 4/3/2
  constexpr int NT = TT / 16;         // 20/19/18
  constexpr int NC = (TT + 31) / 32;  // 10/10/9
  constexpr int TC = NC * 32;         // 320/320/288
  constexpr int TPAD = 328;
  __shared__ __bf16 Plds[64 * TPAD];  // 41984 B
  __shared__ unsigned Vt32[64 * 20];  // 5120 B
  __shared__ float redf[64 * 4];      // 1024 B

  const int hh = blockIdx.x;
  const long eb = blockIdx.y;
  const int tid = threadIdx.x;
  const int w = tid >> 6, lane = tid & 63, lr = lane & 15, qd = lane >> 4;

  const __bf16* qb = qh + ((long)eb * 144 + qoffG) * 768 + hh * 64;
  const __bf16* kb = kvh + (long)eb * TT * 1536 + hh * 64;
  const __bf16* vb = kb + 768;

  bf16x8 qf[MT][2];
#pragma unroll
  for (int mt = 0; mt < MT; mt++)
#pragma unroll
    for (int kc = 0; kc < 2; kc++)
      qf[mt][kc] = *(const bf16x8*)(qb + (long)(mt*16 + lr)*768 + kc*32 + qd*8);

  f4 sacc[MT][5];
#pragma unroll
  for (int mt = 0; mt < MT; mt++)
#pragma unroll
    for (int j = 0; j < 5; j++) sacc[mt][j] = (f4){0.f,0.f,0.f,0.f};
#pragma unroll
  for (int j = 0; j < 5; j++) {
    const int jj = w + 4*j;
    if (jj < NT) {
      const int t0 = jj * 16;
      bf16x8 kf0 = *(const bf16x8*)(kb + (long)(t0 + lr)*1536 + qd*8);
      bf16x8 kf1 = *(const bf16x8*)(kb + (long)(t0 + lr)*1536 + 32 + qd*8);
#pragma unroll
      for (int mt = 0; mt < MT; mt++) {
        sacc[mt][j] = __builtin_amdgcn_mfma_f32_16x16x32_bf16(qf[mt][0], kf0, sacc[mt][j], 0,0,0);
        sacc[mt][j] = __builtin_amdgcn_mfma_f32_16x16x32_bf16(qf[mt][1], kf1, sacc[mt][j], 0,0,0);
      }
    }
  }

  float rowmax[MT][4], linv[MT][4], ps[MT][4];
#pragma unroll
  for (int mt = 0; mt < MT; mt++)
#pragma unroll
    for (int r = 0; r < 4; r++) {
      float m = -1e30f;
#pragma unroll
      for (int j = 0; j < 5; j++)
        if (w + 4*j < NT) m = fmaxf(m, sacc[mt][j][r]);
#pragma unroll
      for (int d = 1; d < 16; d <<= 1) m = fmaxf(m, __shfl_xor(m, d));
      rowmax[mt][r] = m;
    }
  if (lr == 0) {
#pragma unroll
    for (int mt = 0; mt < MT; mt++)
#pragma unroll
      for (int r = 0; r < 4; r++)
        redf[(mt*16 + qd*4 + r)*4 + w] = rowmax[mt][r];
  }
  __syncthreads();
#pragma unroll
  for (int mt = 0; mt < MT; mt++)
#pragma unroll
    for (int r = 0; r < 4; r++) {
      f4 v = *(const f4*)&redf[(mt*16 + qd*4 + r)*4];
      rowmax[mt][r] = fmaxf(fmaxf(v[0],v[1]), fmaxf(v[2],v[3])) * 0.125f;
      ps[mt][r] = 0.f;
    }

#pragma unroll
  for (int j = 0; j < 5; j++) {
    const int jj = w + 4*j;
    if (jj < NT) {
#pragma unroll
      for (int mt = 0; mt < MT; mt++)
#pragma unroll
        for (int r = 0; r < 4; r++) {
          float e = __expf(sacc[mt][j][r]*0.125f - rowmax[mt][r]);
          ps[mt][r] += e;
          Plds[(mt*16 + qd*4 + r)*TPAD + jj*16 + lr] = (__bf16)e;
        }
    }
  }
#pragma unroll
  for (int mt = 0; mt < MT; mt++)
#pragma unroll
    for (int r = 0; r < 4; r++) {
      float s = ps[mt][r];
#pragma unroll
      for (int d = 1; d < 16; d <<= 1) s += __shfl_xor(s, d);
      ps[mt][r] = s;
    }
  __syncthreads();
  if (lr == 0) {
#pragma unroll
    for (int mt = 0; mt < MT; mt++)
#pragma unroll
      for (int r = 0; r < 4; r++)
        redf[(mt*16 + qd*4 + r)*4 + w] = ps[mt][r];
  }
  if (TC > TT) {
    for (int idx = tid; idx < 64*(TC-TT); idx += 256) {
      const int rr = idx / (TC-TT), cc = idx % (TC-TT);
      Plds[rr*TPAD + TT + cc] = (__bf16)0.f;
    }
  }
  __syncthreads();
#pragma unroll
  for (int mt = 0; mt < MT; mt++)
#pragma unroll
    for (int r = 0; r < 4; r++) {
      f4 v = *(const f4*)&redf[(mt*16 + qd*4 + r)*4];
      linv[mt][r] = 1.f / (v[0]+v[1]+v[2]+v[3]);
    }

  f4 oacc[MT];
#pragma unroll
  for (int mt = 0; mt < MT; mt++) oacc[mt] = (f4){0.f,0.f,0.f,0.f};
  const int n0 = w * 16;
  for (int c = 0; c < NC; c++) {
    {
      const int tp = tid & 15, dq = tid >> 4;
      const int t0v = c*32 + tp*2;
      u16x4 v0 = (u16x4){0,0,0,0}, v1 = (u16x4){0,0,0,0};
      if (t0v < TT)     v0 = *(const u16x4*)(vb + (long)t0v*1536 + dq*4);
      if (t0v + 1 < TT) v1 = *(const u16x4*)(vb + (long)(t0v+1)*1536 + dq*4);
#pragma unroll
      for (int i = 0; i < 4; i++)
        Vt32[(dq*4 + i)*20 + tp] = ((unsigned)v1[i] << 16) | (unsigned)v0[i];
    }
    __syncthreads();
    bf16x8 vf = *(const bf16x8*)&Vt32[(n0 + lr)*20 + qd*4];
#pragma unroll
    for (int mt = 0; mt < MT; mt++) {
      bf16x8 pf = *(const bf16x8*)&Plds[(mt*16 + lr)*TPAD + c*32 + qd*8];
      oacc[mt] = __builtin_amdgcn_mfma_f32_16x16x32_bf16(pf, vf, oacc[mt], 0,0,0);
    }
    __syncthreads();
  }

  __bf16* ob = att + ((long)eb*144 + qoffG)*768 + hh*64 + n0 + lr;
#pragma unroll
  for (int mt = 0; mt < MT; mt++)
#pragma unroll
    for (int r = 0; r < 4; r++) {
      const int row = mt*16 + qd*4 + r;
      ob[(long)row * 768] = (__bf16)(oacc[mt][r] * linv[mt][r]);
    }
}

// ---------------------------------------------------------------- RMSNorm
__global__ __launch_bounds__(256) void rmsnorm_kernel(
    const float* __restrict__ in, const float* __restrict__ w,
    const float* __restrict__ g, float* __restrict__ out) {
  const long r = blockIdx.x;
  const int tid = threadIdx.x;
  const float* src = in + r*4096;
  f4 vv[4]; float s2 = 0.f;
#pragma unroll
  for (int i = 0; i < 4; i++) {
    vv[i] = *(const f4*)(src + i*1024 + tid*4);
    s2 += vv[i][0]*vv[i][0] + vv[i][1]*vv[i][1] + vv[i][2]*vv[i][2] + vv[i][3]*vv[i][3];
  }
#pragma unroll
  for (int off = 32; off; off >>= 1) s2 += __shfl_down(s2, off);
  __shared__ float red[4];
  if ((tid & 63) == 0) red[tid >> 6] = s2;
  __syncthreads();
  const float ms = (red[0]+red[1]+red[2]+red[3]) * (1.f/4096.f);
  const float scl = rsqrtf(ms + 1e-6f);
#pragma unroll
  for (int i = 0; i < 4; i++) {
    const int o = i*1024 + tid*4;
    f4 wv = *(const f4*)(w + o);
    f4 gv = *(const f4*)(g + o);
    f4 res = vv[i] * scl * wv * gv;
    *(f4*)(out + r*4096 + o) = res;
  }
}

// ================================================================ launch
extern "C" void kernel_launch(void* const* d_in, const int* in_sizes, int n_in,
                              void* d_out, int out_size, void* d_ws, size_t ws_size,
                              hipStream_t stream) {
  const float* x          = (const float*)d_in[0];
  const float* gate_ln_w  = (const float*)d_in[1];
  const float* gate_ln_b  = (const float*)d_in[2];
  const float* gate_w     = (const float*)d_in[3];
  const float* gate_b     = (const float*)d_in[4];
  const float* exp_in_w   = (const float*)d_in[5];
  const float* exp_in_b   = (const float*)d_in[6];
  const float* exp_query  = (const float*)d_in[7];
  const float* ln1_w      = (const float*)d_in[8];
  const float* ln1_b      = (const float*)d_in[9];
  const float* ln1kv_w    = (const float*)d_in[10];
  const float* ln1kv_b    = (const float*)d_in[11];
  const float* ln2_w      = (const float*)d_in[12];
  const float* ln2_b      = (const float*)d_in[13];
  const float* attn_in_w  = (const float*)d_in[14];
  const float* attn_in_b  = (const float*)d_in[15];
  const float* attn_out_w = (const float*)d_in[16];
  const float* attn_out_b = (const float*)d_in[17];
  const float* ls1        = (const float*)d_in[18];
  const float* ls2        = (const float*)d_in[19];
  const float* fc_w       = (const float*)d_in[20];
  const float* fc_b       = (const float*)d_in[21];
  const float* proj_w     = (const float*)d_in[22];
  const float* proj_b     = (const float*)d_in[23];
  const float* out_w      = (const float*)d_in[24];
  const float* out_b      = (const float*)d_in[25];
  const float* rms_w      = (const float*)d_in[26];
  const float* out_gain   = (const float*)d_in[27];
  float* out = (float*)d_out;

  // ---- workspace layout (byte offsets), total 132,218,880 B (unchanged)
  char* W = (char*)d_ws;
  float*   gw     = (float*)(W + 0);             // 98,304 B; dead after expert gemm
  float*   bsum   = (float*)(W + 0);             // alias gw (out-proj bias sum, 16 KB)
  float*   t      = (float*)(W + 98304);
  __bf16*  qn     = (__bf16*)(W + 14254080);     // alias att; tb_cat at the end
  __bf16*  tbcat  = (__bf16*)(W + 14254080);     // [1152][3072] bf16 = 7,077,888 B
  __bf16*  qh     = (__bf16*)(W + 21331968);
  __bf16*  kvn    = (__bf16*)(W + 28409856);
  __bf16*  kvh    = (__bf16*)(W + 44138496);     // alias mid, outw_cat
  __bf16*  mid    = (__bf16*)(W + 44138496);
  __bf16*  outwc  = (__bf16*)(W + 44138496);     // [4096][3072] bf16 = 25.2 MB <= 31.4 MB
  __bf16*  h      = (__bf16*)(W + 75595776);
  float*   mixed  = (float*)(W + 75595776);      // alias h (h dead by then)
  __bf16*  wbuf   = (__bf16*)(W + 113344512);    // 6.29 MB weights
  __bf16*  xb     = (__bf16*)(W + 119635968);    // x in bf16, 12.58 MB (tail)
  const size_t NEED = 132218880ull;
  if (ws_size < NEED) return;

  // ---- gating (writes xb as a side effect)
  gate_kernel<<<6144, 256, 0, stream>>>(x, gate_ln_w, gate_ln_b, gate_w, gate_b, gw, xb);

  // ---- expert input proj: h[e] = gate_e * (x @ exp_in_w[e]) + bias
  transpose_cvt<<<dim3(24,32,4), 256, 0, stream>>>(exp_in_w, wbuf, 768, 1024, 786432, 786432);
  { GemmP p{ xb, 0, 1024, wbuf, 786432, 1024, h, 4718592, 768,
             exp_in_b, 768, gw, 0, 1024 };
    gemm128<4,true><<<dim3(48,6,4), 256, 0, stream>>>(p); }
  init_t_kernel<<<3456, 256, 0, stream>>>(exp_query, t);

  const int ST[3]  = {320, 304, 288};
  const int SQ[3]  = {64, 48, 32};
  const int QO[3]  = {0, 64, 112};
  const int LO[3]  = {0, 256, 512};

  for (int li = 0; li < 2; li++) {
    transpose_cvt<<<dim3(72,24,4), 256, 0, stream>>>(
        attn_in_w + (long)li*768*2304, wbuf, 2304, 768, 3538944, 1769472);
    ln_rows_kernel<<<4608, 256, 0, stream>>>(t, qn, ln1_w + li*768, ln1_b + li*768);
    { GemmP p{ qn, 884736, 768, wbuf, 1769472, 768, qh, 884736, 768,
               attn_in_b + li*2304, 4608, nullptr, 0, 768 };
      gemm128<0,true><<<dim3(9,6,4), 256, 0, stream>>>(p); }
    for (int s = 0; s < 3; s++) {
      const int T = ST[s];
      ln_kv_kernel<<<32*T, 256, 0, stream>>>(h, exp_query, kvn,
          ln1kv_w + li*768, ln1kv_b + li*768, T, SQ[s], QO[s], LO[s]);
      { GemmP p{ kvn, (long)8*T*768, 768, wbuf + 768*768, 1769472, 768,
                 kvh, (long)8*T*1536, 1536,
                 attn_in_b + li*2304 + 768, 4608, nullptr, 0, 768 };
        gemm128<0,true><<<dim3(8*T/128,12,4), 256, 0, stream>>>(p); }
      if (s == 0)
        attn_mfma_kernel<64,320><<<dim3(12,32), 256, 0, stream>>>(qh, kvh, qn, QO[s]);
      else if (s == 1)
        attn_mfma_kernel<48,304><<<dim3(12,32), 256, 0, stream>>>(qh, kvh, qn, QO[s]);
      else
        attn_mfma_kernel<32,288><<<dim3(12,32), 256, 0, stream>>>(qh, kvh, qn, QO[s]);
    }
    // attn out proj with split-K=2 (z = half*4 + e), atomic += into t
    transpose_cvt<<<dim3(24,24,4), 256, 0, stream>>>(
        attn_out_w + (long)li*589824, wbuf, 768, 768, 1179648, 589824);
    { GemmP p{ qn /*att*/, 884736, 768, wbuf, 589824, 768, t, 884736, 768,
               attn_out_b + li*768, 1536, ls1 + li*768, 1536, 768 };
      gemm128<6,false><<<dim3(9,6,8), 256, 0, stream>>>(p); }
    ln_rows_kernel<<<4608, 256, 0, stream>>>(t, qn, ln2_w + li*768, ln2_b + li*768);
    transpose_cvt<<<dim3(96,24,4), 256, 0, stream>>>(
        fc_w + (long)li*768*3072, wbuf, 3072, 768, 4718592, 2359296);
    { GemmP p{ qn, 884736, 768, wbuf, 2359296, 768, mid, 3538944, 3072,
               fc_b + li*3072, 6144, nullptr, 0, 768 };
      gemm128<1,true><<<dim3(9,24,4), 256, 0, stream>>>(p); }
    transpose_cvt<<<dim3(24,96,4), 256, 0, stream>>>(
        proj_w + (long)li*3072*768, wbuf, 768, 3072, 4718592, 2359296);
    { GemmP p{ mid, 3538944, 3072, wbuf, 2359296, 3072, t, 884736, 768,
               proj_b + li*768, 1536, ls2 + li*768, 1536, 3072 };
      gemm128<6,false><<<dim3(9,6,8), 256, 0, stream>>>(p); }
  }

  // ---- final out proj as ONE GEMM with K concatenated over experts (K=3072):
  // mixed[m][n] = sum_e t[e][m][:] @ out_w[e][:][n] + sum_e out_b[e][n]
  cvt_tcat_kernel<<<3456, 256, 0, stream>>>(t, tbcat);
  bias_sum_kernel<<<16, 256, 0, stream>>>(out_b, bsum);
  // outwc[n][e*768+k] = out_w[e][k][n]; dst row stride 3072, per-e col offset 768
  transpose_cvt<<<dim3(128,24,4), 256, 0, stream>>>(out_w, outwc, 4096, 3072, 3145728, 768);
  { GemmP p{ tbcat, 0, 3072, outwc, 0, 3072, mixed, 0, 4096,
             bsum, 0, nullptr, 0, 3072 };
    gemm128<0,false><<<dim3(9,32,1), 256, 0, stream>>>(p); }
  rmsnorm_kernel<<<1152, 256, 0, stream>>>(mixed, rms_w, out_gain, out);
}

// Round 3
// 1338.736 us; speedup vs baseline: 1.4128x; 1.0579x over previous
//
#include <hip/hip_runtime.h>

typedef __attribute__((ext_vector_type(4))) float f4;
typedef __attribute__((ext_vector_type(8))) __bf16 bf16x8;
typedef __attribute__((ext_vector_type(4))) __bf16 bf16x4;
typedef __attribute__((ext_vector_type(4))) unsigned short u16x4;

// dims: E=4 B=8 L=768 C=1024 H=768 Q=144 NH=12 HD=64 O=4096 NL=2 MLP=3072
// stages: Sq={64,48,32} qoff={0,64,112}; T={320,304,288}; loff={0,256,512}

// async global->LDS, 16B per lane, wave-uniform LDS base + lane*16
#define GLD16(gp, lp)                                                        \
  __builtin_amdgcn_global_load_lds(                                          \
      (__attribute__((address_space(1))) void*)(gp),                         \
      (__attribute__((address_space(3))) void*)(lp), 16, 0, 0)

// ---------------------------------------------------------------- gate (+x->bf16 fused)
__global__ __launch_bounds__(256) void gate_kernel(
    const float* __restrict__ x, const float* __restrict__ lnw,
    const float* __restrict__ lnb, const float* __restrict__ gwm,
    const float* __restrict__ gb, float* __restrict__ out,
    __bf16* __restrict__ xb) {
  const long r = blockIdx.x;
  const int tid = threadIdx.x;
  f4 v = *(const f4*)(x + r * 1024 + tid * 4);
  bf16x4 xo;
  xo[0] = (__bf16)v[0]; xo[1] = (__bf16)v[1]; xo[2] = (__bf16)v[2]; xo[3] = (__bf16)v[3];
  *(bf16x4*)(xb + r * 1024 + tid * 4) = xo;
  float s1 = v[0] + v[1] + v[2] + v[3];
  float s2 = v[0]*v[0] + v[1]*v[1] + v[2]*v[2] + v[3]*v[3];
#pragma unroll
  for (int off = 32; off; off >>= 1) { s1 += __shfl_down(s1, off); s2 += __shfl_down(s2, off); }
  __shared__ float red[8];
  const int wv = tid >> 6;
  if ((tid & 63) == 0) { red[wv*2] = s1; red[wv*2+1] = s2; }
  __syncthreads();
  const float sum = red[0]+red[2]+red[4]+red[6];
  const float sq  = red[1]+red[3]+red[5]+red[7];
  const float mean = sum * (1.f/1024.f);
  const float var  = sq * (1.f/1024.f) - mean*mean;
  const float rstd = rsqrtf(var + 1e-5f);
  f4 lw = *(const f4*)(lnw + tid*4);
  f4 lb = *(const f4*)(lnb + tid*4);
  f4 acc = {0.f,0.f,0.f,0.f};
#pragma unroll
  for (int i = 0; i < 4; i++) {
    float n = (v[i]-mean)*rstd*lw[i] + lb[i];
    f4 g = *(const f4*)(gwm + (long)(tid*4+i)*4);
    acc += n * g;
  }
#pragma unroll
  for (int off = 32; off; off >>= 1) {
    acc[0] += __shfl_down(acc[0], off); acc[1] += __shfl_down(acc[1], off);
    acc[2] += __shfl_down(acc[2], off); acc[3] += __shfl_down(acc[3], off);
  }
  __shared__ f4 red4[4];
  if ((tid & 63) == 0) red4[wv] = acc;
  __syncthreads();
  if (tid == 0) {
    f4 tot = red4[0] + red4[1] + red4[2] + red4[3];
    float lg[4], mx = -1e30f;
#pragma unroll
    for (int e = 0; e < 4; e++) {
      float tv = tot[e] + gb[e];
      tv = fminf(15.f, fmaxf(-15.f, tv));
      lg[e] = tv; mx = fmaxf(mx, tv);
    }
    float den = 0.f;
#pragma unroll
    for (int e = 0; e < 4; e++) { float ev = __expf(lg[e]-mx); lg[e] = ev; den += ev; }
    const float inv = 1.f/den;
    f4 o;
#pragma unroll
    for (int e = 0; e < 4; e++) o[e] = lg[e]*inv;
    *(f4*)(out + r*4) = o;
  }
}

// ------------------------------------------------- weight transpose+cvt
// dst[dxo + n*K + k] = (bf16)src[so + k*srcLd + n]; K is dst row stride.
__global__ __launch_bounds__(256) void transpose_cvt(
    const float* __restrict__ src, __bf16* __restrict__ dst,
    int srcLd, int K, long srcZ, long dstZ) {
  __shared__ float tile[32][33];
  const long so = (long)blockIdx.z * srcZ;
  const long dxo = (long)blockIdx.z * dstZ;
  const int n0 = blockIdx.x * 32, k0 = blockIdx.y * 32;
  const int tx = threadIdx.x & 31, ty = threadIdx.x >> 5;
#pragma unroll
  for (int i = ty; i < 32; i += 8)
    tile[i][tx] = src[so + (long)(k0 + i) * srcLd + n0 + tx];
  __syncthreads();
#pragma unroll
  for (int i = ty; i < 32; i += 8)
    dst[dxo + (long)(n0 + i) * K + k0 + tx] = (__bf16)tile[tx][i];
}

// ---------------------------------------------------------------- t -> tb_cat (K-concat over experts)
__global__ __launch_bounds__(256) void cvt_tcat_kernel(
    const float* __restrict__ t, __bf16* __restrict__ o) {
  const long i4 = ((long)blockIdx.x * 256 + threadIdx.x) * 4;
  const int e = (int)(i4 / 884736);
  const int rem = (int)(i4 % 884736);
  const int m = rem / 768, k = rem % 768;
  f4 v = *(const f4*)(t + i4);
  bf16x4 w;
  w[0] = (__bf16)v[0]; w[1] = (__bf16)v[1]; w[2] = (__bf16)v[2]; w[3] = (__bf16)v[3];
  *(bf16x4*)(o + (long)m * 3072 + e * 768 + k) = w;
}

// ---------------------------------------------------------------- bias sum over experts
__global__ __launch_bounds__(256) void bias_sum_kernel(
    const float* __restrict__ b, float* __restrict__ o) {
  const int i = blockIdx.x * 256 + threadIdx.x;  // 4096 total
  o[i] = b[i] + b[4096 + i] + b[8192 + i] + b[12288 + i];
}

// ---------------------------------------------------------------- LN (t rows, fp32 -> bf16)
__global__ __launch_bounds__(256) void ln_rows_kernel(
    const float* __restrict__ in, __bf16* __restrict__ out,
    const float* __restrict__ w, const float* __restrict__ b) {
  const long r = blockIdx.x;
  const int e = (int)(r / 1152);
  const float* src = in + r * 768;
  const int tid = threadIdx.x;
  float v0 = src[tid], v1 = src[tid+256], v2 = src[tid+512];
  float s1 = v0+v1+v2, s2 = v0*v0+v1*v1+v2*v2;
#pragma unroll
  for (int off = 32; off; off >>= 1) { s1 += __shfl_down(s1, off); s2 += __shfl_down(s2, off); }
  __shared__ float red[8];
  const int wv = tid >> 6;
  if ((tid & 63) == 0) { red[wv*2] = s1; red[wv*2+1] = s2; }
  __syncthreads();
  const float sum = red[0]+red[2]+red[4]+red[6];
  const float sq  = red[1]+red[3]+red[5]+red[7];
  const float mean = sum * (1.f/768.f);
  const float var  = sq * (1.f/768.f) - mean*mean;
  const float rstd = rsqrtf(var + 1e-5f);
  const float* wp = w + (long)e * 1536;
  const float* bp = b + (long)e * 1536;
  __bf16* dst = out + r * 768;
  dst[tid]     = (__bf16)((v0-mean)*rstd*wp[tid]     + bp[tid]);
  dst[tid+256] = (__bf16)((v1-mean)*rstd*wp[tid+256] + bp[tid+256]);
  dst[tid+512] = (__bf16)((v2-mean)*rstd*wp[tid+512] + bp[tid+512]);
}

// ---------------------------------------------------------------- LN (kv gather, one stage)
__global__ __launch_bounds__(256) void ln_kv_kernel(
    const __bf16* __restrict__ h, const float* __restrict__ query,
    __bf16* __restrict__ out, const float* __restrict__ w, const float* __restrict__ b,
    int T, int Sq, int qoffG, int loff) {
  const long r = blockIdx.x;
  const int e = (int)(r / (8*T));
  const int rem = (int)(r % (8*T));
  const int bb = rem / T;
  const int p = rem % T;
  const int tid = threadIdx.x;
  float v0, v1, v2;
  if (p < Sq) {
    const float* src = query + ((long)e * 144 + qoffG + p) * 768;
    v0 = src[tid]; v1 = src[tid+256]; v2 = src[tid+512];
  } else {
    const __bf16* src = h + (((long)e * 8 + bb) * 768 + loff + (p - Sq)) * 768;
    v0 = (float)src[tid]; v1 = (float)src[tid+256]; v2 = (float)src[tid+512];
  }
  float s1 = v0+v1+v2, s2 = v0*v0+v1*v1+v2*v2;
#pragma unroll
  for (int off = 32; off; off >>= 1) { s1 += __shfl_down(s1, off); s2 += __shfl_down(s2, off); }
  __shared__ float red[8];
  const int wv = tid >> 6;
  if ((tid & 63) == 0) { red[wv*2] = s1; red[wv*2+1] = s2; }
  __syncthreads();
  const float sum = red[0]+red[2]+red[4]+red[6];
  const float sq  = red[1]+red[3]+red[5]+red[7];
  const float mean = sum * (1.f/768.f);
  const float var  = sq * (1.f/768.f) - mean*mean;
  const float rstd = rsqrtf(var + 1e-5f);
  const float* wp = w + (long)e * 1536;
  const float* bp2 = b + (long)e * 1536;
  __bf16* dst = out + r * 768;
  dst[tid]     = (__bf16)((v0-mean)*rstd*wp[tid]     + bp2[tid]);
  dst[tid+256] = (__bf16)((v1-mean)*rstd*wp[tid+256] + bp2[tid+256]);
  dst[tid+512] = (__bf16)((v2-mean)*rstd*wp[tid+512] + bp2[tid+512]);
}

// ---------------------------------------------------------------- t init
__global__ __launch_bounds__(256) void init_t_kernel(
    const float* __restrict__ query, float* __restrict__ t) {
  const long i4 = ((long)blockIdx.x * 256 + threadIdx.x) * 4;
  const int e = (int)(i4 / 884736);
  const int rq = (int)(i4 % 110592);
  *(f4*)(t + i4) = *(const f4*)(query + (long)e * 110592 + rq);
}

// ---------------------------------------------------------------- MFMA GEMM
// A is ALWAYS bf16 [M][K] row-major; Bt bf16 [N][K] row-major.
// MODE 0: C=acc+bias           | 1: gelu(acc+bias)
// MODE 4: C = vec[m*4+z]*acc + bias (row gate)
// MODE 6: split-K: z=(half*4+e); atomicAdd(C, vec[n]*(acc + half0?bias:0))
// Staging: global_load_lds dwordx4 into 4-slot linear LDS ring, prefetch depth 3,
// counted vmcnt + raw s_barrier per K-step (T3/T4-minimum). XCD-chunked swizzle.
struct GemmP {
  const __bf16* A; long sAz; int lda;
  const __bf16* Bt; long sBz; int ldb;
  void* C; long sCz; int ldc;
  const float* bias; long sBiasZ;
  const float* vec; long sVecZ;
  int K;
};

template<int MODE, bool C_BF16>
__global__ __launch_bounds__(256) void gemm128(GemmP p) {
  __shared__ __bf16 As[4][128][32];
  __shared__ __bf16 Bs[4][128][32];

  // bijective XCD-chunked swizzle (m204): consecutive original ids -> same XCD
  const int gx = gridDim.x, gy = gridDim.y;
  const int nwg = gx * gy * gridDim.z;
  const int hw = blockIdx.x + gx * (blockIdx.y + gy * blockIdx.z);
  const int q8 = nwg >> 3, r8 = nwg & 7;
  const int xcd = hw & 7, off8 = hw >> 3;
  const int id = (xcd < r8 ? xcd * (q8 + 1) : r8 * (q8 + 1) + (xcd - r8) * q8) + off8;
  const int bidx = id % gx;
  const int rem0 = id / gx;
  const int bidy = rem0 % gy;
  const int z = rem0 / gy;

  int e = z, koff = 0, KK = p.K;
  if (MODE == 6) { e = z & 3; KK = p.K >> 1; koff = (z >> 2) * KK; }

  const __bf16* Ab = p.A + (long)e * p.sAz + koff;
  const __bf16* Bb = p.Bt + (long)e * p.sBz + koff;
  const float* bias = p.bias + (long)e * p.sBiasZ;
  const float* vec = (MODE == 4 || MODE == 6) ? (p.vec + (long)e * p.sVecZ) : nullptr;

  const int m0 = bidx * 128, n0 = bidy * 128;
  const int tid = threadIdx.x;
  const int w = tid >> 6, lane = tid & 63;
  const int lr = lane & 15, qd = lane >> 4;
  const int wm = (w & 1) * 64, wn = (w >> 1) * 64;

  // staging map: wave w owns rows [w*32, w*32+32); lane l -> row w*32+(l>>2),
  // col (l&3)*8 bf16 (16B). LDS dest = wave-uniform base + lane*16 (linear).
  const int sr = w * 32 + (lane >> 2);
  const int sc = (lane & 3) * 8;
  const int lda = p.lda, ldb = p.ldb;
  const __bf16* gA = Ab + (long)(m0 + sr) * lda + sc;
  const __bf16* gB = Bb + (long)(n0 + sr) * ldb + sc;

  f4 acc[4][4];
#pragma unroll
  for (int i = 0; i < 4; i++)
#pragma unroll
    for (int j = 0; j < 4; j++) acc[i][j] = (f4){0.f, 0.f, 0.f, 0.f};

  const int nk = KK >> 5;

#define STAGE(buf, t)                                        \
  do {                                                       \
    const __bf16* a_ = gA + (long)(t) * 32;                  \
    const __bf16* b_ = gB + (long)(t) * 32;                  \
    GLD16(a_,                 &As[buf][w * 32][0]);          \
    GLD16(a_ + 16 * lda,      &As[buf][w * 32 + 16][0]);     \
    GLD16(b_,                 &Bs[buf][w * 32][0]);          \
    GLD16(b_ + 16 * ldb,      &Bs[buf][w * 32 + 16][0]);     \
  } while (0)

  // prologue: prefetch depth 3 (12 loads/wave in flight)
  STAGE(0, 0);
  if (nk > 1) STAGE(1, 1);
  if (nk > 2) STAGE(2, 2);

  for (int t = 0; t < nk; ++t) {
    const int rem = nk - 1 - t;  // staged-beyond-t = min(2, rem) -> 4 loads each
    if (rem >= 2)      asm volatile("s_waitcnt vmcnt(8)" ::: "memory");
    else if (rem == 1) asm volatile("s_waitcnt vmcnt(4)" ::: "memory");
    else               asm volatile("s_waitcnt vmcnt(0)" ::: "memory");
    __builtin_amdgcn_s_barrier();          // all waves' tile-t loads landed
    __builtin_amdgcn_sched_barrier(0);
    if (t + 3 < nk) STAGE((t + 3) & 3, t + 3);  // issue-ahead; lands >=3 iters later
    __builtin_amdgcn_sched_barrier(0);
    const int cur = t & 3;
    bf16x8 af[4], bfr[4];
#pragma unroll
    for (int i = 0; i < 4; i++) af[i] = *(const bf16x8*)&As[cur][wm + i*16 + lr][qd*8];
#pragma unroll
    for (int j = 0; j < 4; j++) bfr[j] = *(const bf16x8*)&Bs[cur][wn + j*16 + lr][qd*8];
#pragma unroll
    for (int i = 0; i < 4; i++)
#pragma unroll
      for (int j = 0; j < 4; j++)
        acc[i][j] = __builtin_amdgcn_mfma_f32_16x16x32_bf16(af[i], bfr[j], acc[i][j], 0, 0, 0);
    // no trailing barrier: next iter's top barrier orders buffer reuse
    // (STAGE in iter t+1 targets buf (t+4)&3 == (t)&3, read-retired by then? no:
    //  it targets (t+1+3)&3 = (t)&3 — reads of buf t&3 retired before this wave's
    //  MFMAs issued, and the top-of-iter-(t+1) barrier globalizes that.)
  }
#undef STAGE

  const long cOff = (MODE == 6) ? (long)e * p.sCz : (long)z * p.sCz;
  float* Cf = (float*)p.C + cOff;
  __bf16* Cb = (__bf16*)p.C + cOff;
#pragma unroll
  for (int i = 0; i < 4; i++) {
    const int rbase = m0 + wm + i*16 + qd*4;
#pragma unroll
    for (int j = 0; j < 4; j++) {
      const int col = n0 + wn + j*16 + lr;
      const float bcol = bias[col];
      f4 v = acc[i][j];
#pragma unroll
      for (int r = 0; r < 4; r++) {
        const long o = (long)(rbase + r) * p.ldc + col;
        const float xx = v[r];
        if (MODE == 0) {
          const float y = xx + bcol;
          if (C_BF16) Cb[o] = (__bf16)y; else Cf[o] = y;
        } else if (MODE == 1) {
          const float y = xx + bcol;
          const float g = 0.5f * y * (1.0f + erff(y * 0.70710678118654752f));
          if (C_BF16) Cb[o] = (__bf16)g; else Cf[o] = g;
        } else if (MODE == 4) {
          const float y = vec[(long)(rbase + r) * 4 + z] * xx + bcol;
          if (C_BF16) Cb[o] = (__bf16)y; else Cf[o] = y;
        } else if (MODE == 6) {
          unsafeAtomicAdd(&Cf[o], vec[col] * (xx + (koff == 0 ? bcol : 0.f)));
        }
      }
    }
  }
}

// ---------------------------------------------------------------- MFMA attention
template<int TSQ, int TT>
__global__ __launch_bounds__(256) void attn_mfma_kernel(
    const __bf16* __restrict__ qh, const __bf16* __restrict__ kvh,
    __bf16* __restrict__ att, int qoffG) {
  constexpr int MT = TSQ / 16;        // 4/3/2
  constexpr int NT = TT / 16;         // 20/19/18
  constexpr int NC = (TT + 31) / 32;  // 10/10/9
  constexpr int TC = NC * 32;         // 320/320/288
  constexpr int TPAD = 328;
  __shared__ __bf16 Plds[64 * TPAD];  // 41984 B
  __shared__ unsigned Vt32[64 * 20];  // 5120 B
  __shared__ float redf[64 * 4];      // 1024 B

  const int hh = blockIdx.x;
  const long eb = blockIdx.y;
  const int tid = threadIdx.x;
  const int w = tid >> 6, lane = tid & 63, lr = lane & 15, qd = lane >> 4;

  const __bf16* qb = qh + ((long)eb * 144 + qoffG) * 768 + hh * 64;
  const __bf16* kb = kvh + (long)eb * TT * 1536 + hh * 64;
  const __bf16* vb = kb + 768;

  bf16x8 qf[MT][2];
#pragma unroll
  for (int mt = 0; mt < MT; mt++)
#pragma unroll
    for (int kc = 0; kc < 2; kc++)
      qf[mt][kc] = *(const bf16x8*)(qb + (long)(mt*16 + lr)*768 + kc*32 + qd*8);

  f4 sacc[MT][5];
#pragma unroll
  for (int mt = 0; mt < MT; mt++)
#pragma unroll
    for (int j = 0; j < 5; j++) sacc[mt][j] = (f4){0.f,0.f,0.f,0.f};
#pragma unroll
  for (int j = 0; j < 5; j++) {
    const int jj = w + 4*j;
    if (jj < NT) {
      const int t0 = jj * 16;
      bf16x8 kf0 = *(const bf16x8*)(kb + (long)(t0 + lr)*1536 + qd*8);
      bf16x8 kf1 = *(const bf16x8*)(kb + (long)(t0 + lr)*1536 + 32 + qd*8);
#pragma unroll
      for (int mt = 0; mt < MT; mt++) {
        sacc[mt][j] = __builtin_amdgcn_mfma_f32_16x16x32_bf16(qf[mt][0], kf0, sacc[mt][j], 0,0,0);
        sacc[mt][j] = __builtin_amdgcn_mfma_f32_16x16x32_bf16(qf[mt][1], kf1, sacc[mt][j], 0,0,0);
      }
    }
  }

  float rowmax[MT][4], linv[MT][4], ps[MT][4];
#pragma unroll
  for (int mt = 0; mt < MT; mt++)
#pragma unroll
    for (int r = 0; r < 4; r++) {
      float m = -1e30f;
#pragma unroll
      for (int j = 0; j < 5; j++)
        if (w + 4*j < NT) m = fmaxf(m, sacc[mt][j][r]);
#pragma unroll
      for (int d = 1; d < 16; d <<= 1) m = fmaxf(m, __shfl_xor(m, d));
      rowmax[mt][r] = m;
    }
  if (lr == 0) {
#pragma unroll
    for (int mt = 0; mt < MT; mt++)
#pragma unroll
      for (int r = 0; r < 4; r++)
        redf[(mt*16 + qd*4 + r)*4 + w] = rowmax[mt][r];
  }
  __syncthreads();
#pragma unroll
  for (int mt = 0; mt < MT; mt++)
#pragma unroll
    for (int r = 0; r < 4; r++) {
      f4 v = *(const f4*)&redf[(mt*16 + qd*4 + r)*4];
      rowmax[mt][r] = fmaxf(fmaxf(v[0],v[1]), fmaxf(v[2],v[3])) * 0.125f;
      ps[mt][r] = 0.f;
    }

#pragma unroll
  for (int j = 0; j < 5; j++) {
    const int jj = w + 4*j;
    if (jj < NT) {
#pragma unroll
      for (int mt = 0; mt < MT; mt++)
#pragma unroll
        for (int r = 0; r < 4; r++) {
          float e = __expf(sacc[mt][j][r]*0.125f - rowmax[mt][r]);
          ps[mt][r] += e;
          Plds[(mt*16 + qd*4 + r)*TPAD + jj*16 + lr] = (__bf16)e;
        }
    }
  }
#pragma unroll
  for (int mt = 0; mt < MT; mt++)
#pragma unroll
    for (int r = 0; r < 4; r++) {
      float s = ps[mt][r];
#pragma unroll
      for (int d = 1; d < 16; d <<= 1) s += __shfl_xor(s, d);
      ps[mt][r] = s;
    }
  __syncthreads();
  if (lr == 0) {
#pragma unroll
    for (int mt = 0; mt < MT; mt++)
#pragma unroll
      for (int r = 0; r < 4; r++)
        redf[(mt*16 + qd*4 + r)*4 + w] = ps[mt][r];
  }
  if (TC > TT) {
    for (int idx = tid; idx < 64*(TC-TT); idx += 256) {
      const int rr = idx / (TC-TT), cc = idx % (TC-TT);
      Plds[rr*TPAD + TT + cc] = (__bf16)0.f;
    }
  }
  __syncthreads();
#pragma unroll
  for (int mt = 0; mt < MT; mt++)
#pragma unroll
    for (int r = 0; r < 4; r++) {
      f4 v = *(const f4*)&redf[(mt*16 + qd*4 + r)*4];
      linv[mt][r] = 1.f / (v[0]+v[1]+v[2]+v[3]);
    }

  f4 oacc[MT];
#pragma unroll
  for (int mt = 0; mt < MT; mt++) oacc[mt] = (f4){0.f,0.f,0.f,0.f};
  const int n0 = w * 16;
  for (int c = 0; c < NC; c++) {
    {
      const int tp = tid & 15, dq = tid >> 4;
      const int t0v = c*32 + tp*2;
      u16x4 v0 = (u16x4){0,0,0,0}, v1 = (u16x4){0,0,0,0};
      if (t0v < TT)     v0 = *(const u16x4*)(vb + (long)t0v*1536 + dq*4);
      if (t0v + 1 < TT) v1 = *(const u16x4*)(vb + (long)(t0v+1)*1536 + dq*4);
#pragma unroll
      for (int i = 0; i < 4; i++)
        Vt32[(dq*4 + i)*20 + tp] = ((unsigned)v1[i] << 16) | (unsigned)v0[i];
    }
    __syncthreads();
    bf16x8 vf = *(const bf16x8*)&Vt32[(n0 + lr)*20 + qd*4];
#pragma unroll
    for (int mt = 0; mt < MT; mt++) {
      bf16x8 pf = *(const bf16x8*)&Plds[(mt*16 + lr)*TPAD + c*32 + qd*8];
      oacc[mt] = __builtin_amdgcn_mfma_f32_16x16x32_bf16(pf, vf, oacc[mt], 0,0,0);
    }
    __syncthreads();
  }

  __bf16* ob = att + ((long)eb*144 + qoffG)*768 + hh*64 + n0 + lr;
#pragma unroll
  for (int mt = 0; mt < MT; mt++)
#pragma unroll
    for (int r = 0; r < 4; r++) {
      const int row = mt*16 + qd*4 + r;
      ob[(long)row * 768] = (__bf16)(oacc[mt][r] * linv[mt][r]);
    }
}

// ---------------------------------------------------------------- RMSNorm
__global__ __launch_bounds__(256) void rmsnorm_kernel(
    const float* __restrict__ in, const float* __restrict__ w,
    const float* __restrict__ g, float* __restrict__ out) {
  const long r = blockIdx.x;
  const int tid = threadIdx.x;
  const float* src = in + r*4096;
  f4 vv[4]; float s2 = 0.f;
#pragma unroll
  for (int i = 0; i < 4; i++) {
    vv[i] = *(const f4*)(src + i*1024 + tid*4);
    s2 += vv[i][0]*vv[i][0] + vv[i][1]*vv[i][1] + vv[i][2]*vv[i][2] + vv[i][3]*vv[i][3];
  }
#pragma unroll
  for (int off = 32; off; off >>= 1) s2 += __shfl_down(s2, off);
  __shared__ float red[4];
  if ((tid & 63) == 0) red[tid >> 6] = s2;
  __syncthreads();
  const float ms = (red[0]+red[1]+red[2]+red[3]) * (1.f/4096.f);
  const float scl = rsqrtf(ms + 1e-6f);
#pragma unroll
  for (int i = 0; i < 4; i++) {
    const int o = i*1024 + tid*4;
    f4 wv = *(const f4*)(w + o);
    f4 gv = *(const f4*)(g + o);
    f4 res = vv[i] * scl * wv * gv;
    *(f4*)(out + r*4096 + o) = res;
  }
}

// ================================================================ launch
extern "C" void kernel_launch(void* const* d_in, const int* in_sizes, int n_in,
                              void* d_out, int out_size, void* d_ws, size_t ws_size,
                              hipStream_t stream) {
  const float* x          = (const float*)d_in[0];
  const float* gate_ln_w  = (const float*)d_in[1];
  const float* gate_ln_b  = (const float*)d_in[2];
  const float* gate_w     = (const float*)d_in[3];
  const float* gate_b     = (const float*)d_in[4];
  const float* exp_in_w   = (const float*)d_in[5];
  const float* exp_in_b   = (const float*)d_in[6];
  const float* exp_query  = (const float*)d_in[7];
  const float* ln1_w      = (const float*)d_in[8];
  const float* ln1_b      = (const float*)d_in[9];
  const float* ln1kv_w    = (const float*)d_in[10];
  const float* ln1kv_b    = (const float*)d_in[11];
  const float* ln2_w      = (const float*)d_in[12];
  const float* ln2_b      = (const float*)d_in[13];
  const float* attn_in_w  = (const float*)d_in[14];
  const float* attn_in_b  = (const float*)d_in[15];
  const float* attn_out_w = (const float*)d_in[16];
  const float* attn_out_b = (const float*)d_in[17];
  const float* ls1        = (const float*)d_in[18];
  const float* ls2        = (const float*)d_in[19];
  const float* fc_w       = (const float*)d_in[20];
  const float* fc_b       = (const float*)d_in[21];
  const float* proj_w     = (const float*)d_in[22];
  const float* proj_b     = (const float*)d_in[23];
  const float* out_w      = (const float*)d_in[24];
  const float* out_b      = (const float*)d_in[25];
  const float* rms_w      = (const float*)d_in[26];
  const float* out_gain   = (const float*)d_in[27];
  float* out = (float*)d_out;

  // ---- workspace layout (byte offsets), total 132,218,880 B (unchanged)
  char* W = (char*)d_ws;
  float*   gw     = (float*)(W + 0);             // 98,304 B; dead after expert gemm
  float*   bsum   = (float*)(W + 0);             // alias gw (out-proj bias sum, 16 KB)
  float*   t      = (float*)(W + 98304);
  __bf16*  qn     = (__bf16*)(W + 14254080);     // alias att; tb_cat at the end
  __bf16*  tbcat  = (__bf16*)(W + 14254080);     // [1152][3072] bf16 = 7,077,888 B
  __bf16*  qh     = (__bf16*)(W + 21331968);
  __bf16*  kvn    = (__bf16*)(W + 28409856);
  __bf16*  kvh    = (__bf16*)(W + 44138496);     // alias mid, outw_cat
  __bf16*  mid    = (__bf16*)(W + 44138496);
  __bf16*  outwc  = (__bf16*)(W + 44138496);     // [4096][3072] bf16 = 25.2 MB <= 31.4 MB
  __bf16*  h      = (__bf16*)(W + 75595776);
  float*   mixed  = (float*)(W + 75595776);      // alias h (h dead by then)
  __bf16*  wbuf   = (__bf16*)(W + 113344512);    // 6.29 MB weights
  __bf16*  xb     = (__bf16*)(W + 119635968);    // x in bf16, 12.58 MB (tail)
  const size_t NEED = 132218880ull;
  if (ws_size < NEED) return;

  // ---- gating (writes xb as a side effect)
  gate_kernel<<<6144, 256, 0, stream>>>(x, gate_ln_w, gate_ln_b, gate_w, gate_b, gw, xb);

  // ---- expert input proj: h[e] = gate_e * (x @ exp_in_w[e]) + bias
  transpose_cvt<<<dim3(24,32,4), 256, 0, stream>>>(exp_in_w, wbuf, 768, 1024, 786432, 786432);
  { GemmP p{ xb, 0, 1024, wbuf, 786432, 1024, h, 4718592, 768,
             exp_in_b, 768, gw, 0, 1024 };
    gemm128<4,true><<<dim3(48,6,4), 256, 0, stream>>>(p); }
  init_t_kernel<<<3456, 256, 0, stream>>>(exp_query, t);

  const int ST[3]  = {320, 304, 288};
  const int SQ[3]  = {64, 48, 32};
  const int QO[3]  = {0, 64, 112};
  const int LO[3]  = {0, 256, 512};

  for (int li = 0; li < 2; li++) {
    transpose_cvt<<<dim3(72,24,4), 256, 0, stream>>>(
        attn_in_w + (long)li*768*2304, wbuf, 2304, 768, 3538944, 1769472);
    ln_rows_kernel<<<4608, 256, 0, stream>>>(t, qn, ln1_w + li*768, ln1_b + li*768);
    { GemmP p{ qn, 884736, 768, wbuf, 1769472, 768, qh, 884736, 768,
               attn_in_b + li*2304, 4608, nullptr, 0, 768 };
      gemm128<0,true><<<dim3(9,6,4), 256, 0, stream>>>(p); }
    for (int s = 0; s < 3; s++) {
      const int T = ST[s];
      ln_kv_kernel<<<32*T, 256, 0, stream>>>(h, exp_query, kvn,
          ln1kv_w + li*768, ln1kv_b + li*768, T, SQ[s], QO[s], LO[s]);
      { GemmP p{ kvn, (long)8*T*768, 768, wbuf + 768*768, 1769472, 768,
                 kvh, (long)8*T*1536, 1536,
                 attn_in_b + li*2304 + 768, 4608, nullptr, 0, 768 };
        gemm128<0,true><<<dim3(8*T/128,12,4), 256, 0, stream>>>(p); }
      if (s == 0)
        attn_mfma_kernel<64,320><<<dim3(12,32), 256, 0, stream>>>(qh, kvh, qn, QO[s]);
      else if (s == 1)
        attn_mfma_kernel<48,304><<<dim3(12,32), 256, 0, stream>>>(qh, kvh, qn, QO[s]);
      else
        attn_mfma_kernel<32,288><<<dim3(12,32), 256, 0, stream>>>(qh, kvh, qn, QO[s]);
    }
    // attn out proj with split-K=2 (z = half*4 + e), atomic += into t
    transpose_cvt<<<dim3(24,24,4), 256, 0, stream>>>(
        attn_out_w + (long)li*589824, wbuf, 768, 768, 1179648, 589824);
    { GemmP p{ qn /*att*/, 884736, 768, wbuf, 589824, 768, t, 884736, 768,
               attn_out_b + li*768, 1536, ls1 + li*768, 1536, 768 };
      gemm128<6,false><<<dim3(9,6,8), 256, 0, stream>>>(p); }
    ln_rows_kernel<<<4608, 256, 0, stream>>>(t, qn, ln2_w + li*768, ln2_b + li*768);
    transpose_cvt<<<dim3(96,24,4), 256, 0, stream>>>(
        fc_w + (long)li*768*3072, wbuf, 3072, 768, 4718592, 2359296);
    { GemmP p{ qn, 884736, 768, wbuf, 2359296, 768, mid, 3538944, 3072,
               fc_b + li*3072, 6144, nullptr, 0, 768 };
      gemm128<1,true><<<dim3(9,24,4), 256, 0, stream>>>(p); }
    transpose_cvt<<<dim3(24,96,4), 256, 0, stream>>>(
        proj_w + (long)li*3072*768, wbuf, 768, 3072, 4718592, 2359296);
    { GemmP p{ mid, 3538944, 3072, wbuf, 2359296, 3072, t, 884736, 768,
               proj_b + li*768, 1536, ls2 + li*768, 1536, 3072 };
      gemm128<6,false><<<dim3(9,6,8), 256, 0, stream>>>(p); }
  }

  // ---- final out proj as ONE GEMM with K concatenated over experts (K=3072)
  cvt_tcat_kernel<<<3456, 256, 0, stream>>>(t, tbcat);
  bias_sum_kernel<<<16, 256, 0, stream>>>(out_b, bsum);
  transpose_cvt<<<dim3(128,24,4), 256, 0, stream>>>(out_w, outwc, 4096, 3072, 3145728, 768);
  { GemmP p{ tbcat, 0, 3072, outwc, 0, 3072, mixed, 0, 4096,
             bsum, 0, nullptr, 0, 3072 };
    gemm128<0,false><<<dim3(9,32,1), 256, 0, stream>>>(p); }
  rmsnorm_kernel<<<1152, 256, 0, stream>>>(mixed, rms_w, out_gain, out);
}

// Round 4
// 1324.832 us; speedup vs baseline: 1.4276x; 1.0105x over previous
//
#include <hip/hip_runtime.h>

typedef __attribute__((ext_vector_type(4))) float f4;
typedef __attribute__((ext_vector_type(8))) __bf16 bf16x8;
typedef __attribute__((ext_vector_type(4))) __bf16 bf16x4;
typedef __attribute__((ext_vector_type(4))) unsigned short u16x4;

// dims: E=4 B=8 L=768 C=1024 H=768 Q=144 NH=12 HD=64 O=4096 NL=2 MLP=3072
// stages: Sq={64,48,32} qoff={0,64,112}; T={320,304,288}; loff={0,256,512}

// async global->LDS, 16B per lane, wave-uniform LDS base + lane*16
#define GLD16(gp, lp)                                                        \
  __builtin_amdgcn_global_load_lds(                                          \
      (__attribute__((address_space(1))) void*)(gp),                         \
      (__attribute__((address_space(3))) void*)(lp), 16, 0, 0)

// ---------------------------------------------------------------- gate (+x->bf16 fused)
__global__ __launch_bounds__(256) void gate_kernel(
    const float* __restrict__ x, const float* __restrict__ lnw,
    const float* __restrict__ lnb, const float* __restrict__ gwm,
    const float* __restrict__ gb, float* __restrict__ out,
    __bf16* __restrict__ xb) {
  const long r = blockIdx.x;
  const int tid = threadIdx.x;
  f4 v = *(const f4*)(x + r * 1024 + tid * 4);
  bf16x4 xo;
  xo[0] = (__bf16)v[0]; xo[1] = (__bf16)v[1]; xo[2] = (__bf16)v[2]; xo[3] = (__bf16)v[3];
  *(bf16x4*)(xb + r * 1024 + tid * 4) = xo;
  float s1 = v[0] + v[1] + v[2] + v[3];
  float s2 = v[0]*v[0] + v[1]*v[1] + v[2]*v[2] + v[3]*v[3];
#pragma unroll
  for (int off = 32; off; off >>= 1) { s1 += __shfl_down(s1, off); s2 += __shfl_down(s2, off); }
  __shared__ float red[8];
  const int wv = tid >> 6;
  if ((tid & 63) == 0) { red[wv*2] = s1; red[wv*2+1] = s2; }
  __syncthreads();
  const float sum = red[0]+red[2]+red[4]+red[6];
  const float sq  = red[1]+red[3]+red[5]+red[7];
  const float mean = sum * (1.f/1024.f);
  const float var  = sq * (1.f/1024.f) - mean*mean;
  const float rstd = rsqrtf(var + 1e-5f);
  f4 lw = *(const f4*)(lnw + tid*4);
  f4 lb = *(const f4*)(lnb + tid*4);
  f4 acc = {0.f,0.f,0.f,0.f};
#pragma unroll
  for (int i = 0; i < 4; i++) {
    float n = (v[i]-mean)*rstd*lw[i] + lb[i];
    f4 g = *(const f4*)(gwm + (long)(tid*4+i)*4);
    acc += n * g;
  }
#pragma unroll
  for (int off = 32; off; off >>= 1) {
    acc[0] += __shfl_down(acc[0], off); acc[1] += __shfl_down(acc[1], off);
    acc[2] += __shfl_down(acc[2], off); acc[3] += __shfl_down(acc[3], off);
  }
  __shared__ f4 red4[4];
  if ((tid & 63) == 0) red4[wv] = acc;
  __syncthreads();
  if (tid == 0) {
    f4 tot = red4[0] + red4[1] + red4[2] + red4[3];
    float lg[4], mx = -1e30f;
#pragma unroll
    for (int e = 0; e < 4; e++) {
      float tv = tot[e] + gb[e];
      tv = fminf(15.f, fmaxf(-15.f, tv));
      lg[e] = tv; mx = fmaxf(mx, tv);
    }
    float den = 0.f;
#pragma unroll
    for (int e = 0; e < 4; e++) { float ev = __expf(lg[e]-mx); lg[e] = ev; den += ev; }
    const float inv = 1.f/den;
    f4 o;
#pragma unroll
    for (int e = 0; e < 4; e++) o[e] = lg[e]*inv;
    *(f4*)(out + r*4) = o;
  }
}

// ------------------------------------------------- weight transpose+cvt
// dst[dxo + n*K + k] = (bf16)src[so + k*srcLd + n]; K is dst row stride.
__global__ __launch_bounds__(256) void transpose_cvt(
    const float* __restrict__ src, __bf16* __restrict__ dst,
    int srcLd, int K, long srcZ, long dstZ) {
  __shared__ float tile[32][33];
  const long so = (long)blockIdx.z * srcZ;
  const long dxo = (long)blockIdx.z * dstZ;
  const int n0 = blockIdx.x * 32, k0 = blockIdx.y * 32;
  const int tx = threadIdx.x & 31, ty = threadIdx.x >> 5;
#pragma unroll
  for (int i = ty; i < 32; i += 8)
    tile[i][tx] = src[so + (long)(k0 + i) * srcLd + n0 + tx];
  __syncthreads();
#pragma unroll
  for (int i = ty; i < 32; i += 8)
    dst[dxo + (long)(n0 + i) * K + k0 + tx] = (__bf16)tile[tx][i];
}

// ---------------------------------------------------------------- t -> tb_cat (K-concat over experts)
__global__ __launch_bounds__(256) void cvt_tcat_kernel(
    const float* __restrict__ t, __bf16* __restrict__ o) {
  const long i4 = ((long)blockIdx.x * 256 + threadIdx.x) * 4;
  const int e = (int)(i4 / 884736);
  const int rem = (int)(i4 % 884736);
  const int m = rem / 768, k = rem % 768;
  f4 v = *(const f4*)(t + i4);
  bf16x4 w;
  w[0] = (__bf16)v[0]; w[1] = (__bf16)v[1]; w[2] = (__bf16)v[2]; w[3] = (__bf16)v[3];
  *(bf16x4*)(o + (long)m * 3072 + e * 768 + k) = w;
}

// ---------------------------------------------------------------- bias sum over experts
__global__ __launch_bounds__(256) void bias_sum_kernel(
    const float* __restrict__ b, float* __restrict__ o) {
  const int i = blockIdx.x * 256 + threadIdx.x;  // 4096 total
  o[i] = b[i] + b[4096 + i] + b[8192 + i] + b[12288 + i];
}

// ---------------------------------------------------------------- LN (t rows, fp32 -> bf16)
__global__ __launch_bounds__(256) void ln_rows_kernel(
    const float* __restrict__ in, __bf16* __restrict__ out,
    const float* __restrict__ w, const float* __restrict__ b) {
  const long r = blockIdx.x;
  const int e = (int)(r / 1152);
  const float* src = in + r * 768;
  const int tid = threadIdx.x;
  float v0 = src[tid], v1 = src[tid+256], v2 = src[tid+512];
  float s1 = v0+v1+v2, s2 = v0*v0+v1*v1+v2*v2;
#pragma unroll
  for (int off = 32; off; off >>= 1) { s1 += __shfl_down(s1, off); s2 += __shfl_down(s2, off); }
  __shared__ float red[8];
  const int wv = tid >> 6;
  if ((tid & 63) == 0) { red[wv*2] = s1; red[wv*2+1] = s2; }
  __syncthreads();
  const float sum = red[0]+red[2]+red[4]+red[6];
  const float sq  = red[1]+red[3]+red[5]+red[7];
  const float mean = sum * (1.f/768.f);
  const float var  = sq * (1.f/768.f) - mean*mean;
  const float rstd = rsqrtf(var + 1e-5f);
  const float* wp = w + (long)e * 1536;
  const float* bp = b + (long)e * 1536;
  __bf16* dst = out + r * 768;
  dst[tid]     = (__bf16)((v0-mean)*rstd*wp[tid]     + bp[tid]);
  dst[tid+256] = (__bf16)((v1-mean)*rstd*wp[tid+256] + bp[tid+256]);
  dst[tid+512] = (__bf16)((v2-mean)*rstd*wp[tid+512] + bp[tid+512]);
}

// ---------------------------------------------------------------- LN (kv gather, one stage)
__global__ __launch_bounds__(256) void ln_kv_kernel(
    const __bf16* __restrict__ h, const float* __restrict__ query,
    __bf16* __restrict__ out, const float* __restrict__ w, const float* __restrict__ b,
    int T, int Sq, int qoffG, int loff) {
  const long r = blockIdx.x;
  const int e = (int)(r / (8*T));
  const int rem = (int)(r % (8*T));
  const int bb = rem / T;
  const int p = rem % T;
  const int tid = threadIdx.x;
  float v0, v1, v2;
  if (p < Sq) {
    const float* src = query + ((long)e * 144 + qoffG + p) * 768;
    v0 = src[tid]; v1 = src[tid+256]; v2 = src[tid+512];
  } else {
    const __bf16* src = h + (((long)e * 8 + bb) * 768 + loff + (p - Sq)) * 768;
    v0 = (float)src[tid]; v1 = (float)src[tid+256]; v2 = (float)src[tid+512];
  }
  float s1 = v0+v1+v2, s2 = v0*v0+v1*v1+v2*v2;
#pragma unroll
  for (int off = 32; off; off >>= 1) { s1 += __shfl_down(s1, off); s2 += __shfl_down(s2, off); }
  __shared__ float red[8];
  const int wv = tid >> 6;
  if ((tid & 63) == 0) { red[wv*2] = s1; red[wv*2+1] = s2; }
  __syncthreads();
  const float sum = red[0]+red[2]+red[4]+red[6];
  const float sq  = red[1]+red[3]+red[5]+red[7];
  const float mean = sum * (1.f/768.f);
  const float var  = sq * (1.f/768.f) - mean*mean;
  const float rstd = rsqrtf(var + 1e-5f);
  const float* wp = w + (long)e * 1536;
  const float* bp2 = b + (long)e * 1536;
  __bf16* dst = out + r * 768;
  dst[tid]     = (__bf16)((v0-mean)*rstd*wp[tid]     + bp2[tid]);
  dst[tid+256] = (__bf16)((v1-mean)*rstd*wp[tid+256] + bp2[tid+256]);
  dst[tid+512] = (__bf16)((v2-mean)*rstd*wp[tid+512] + bp2[tid+512]);
}

// ---------------------------------------------------------------- t init
__global__ __launch_bounds__(256) void init_t_kernel(
    const float* __restrict__ query, float* __restrict__ t) {
  const long i4 = ((long)blockIdx.x * 256 + threadIdx.x) * 4;
  const int e = (int)(i4 / 884736);
  const int rq = (int)(i4 % 110592);
  *(f4*)(t + i4) = *(const f4*)(query + (long)e * 110592 + rq);
}

// ---------------------------------------------------------------- MFMA GEMM
// A is ALWAYS bf16 [M][K] row-major; Bt bf16 [N][K] row-major.
// MODE 0: C=acc+bias           | 1: gelu(acc+bias)
// MODE 4: C = vec[m*4+z]*acc + bias (row gate)
// MODE 6: split-K: z=(half*4+e); atomicAdd(C, vec[n]*(acc + half0?bias:0))
// Staging: global_load_lds dwordx4 into 3-slot linear LDS ring, prefetch depth 2,
// counted vmcnt + raw s_barrier per K-step. BM=128 (48KB LDS, 3 blk/CU) or
// BM=64 (36KB LDS, 4 blk/CU) for small-grid GEMMs. XCD-chunked swizzle.
struct GemmP {
  const __bf16* A; long sAz; int lda;
  const __bf16* Bt; long sBz; int ldb;
  void* C; long sCz; int ldc;
  const float* bias; long sBiasZ;
  const float* vec; long sVecZ;
  int K;
};

template<int MODE, bool C_BF16, int BM>
__global__ __launch_bounds__(256) void gemm128(GemmP p) {
  constexpr int MF = BM / 32;   // m-frags per wave (4 or 2)
  constexpr int AG = BM / 64;   // A-GLD16s per wave per stage (2 or 1)
  constexpr int LPS = AG + 2;   // loads per stage per wave (4 or 3)
  __shared__ __bf16 As[3][BM][32];
  __shared__ __bf16 Bs[3][128][32];

  // bijective XCD-chunked swizzle (m204): consecutive original ids -> same XCD
  const int gx = gridDim.x, gy = gridDim.y;
  const int nwg = gx * gy * gridDim.z;
  const int hw = blockIdx.x + gx * (blockIdx.y + gy * blockIdx.z);
  const int q8 = nwg >> 3, r8 = nwg & 7;
  const int xcd = hw & 7, off8 = hw >> 3;
  const int id = (xcd < r8 ? xcd * (q8 + 1) : r8 * (q8 + 1) + (xcd - r8) * q8) + off8;
  const int bidx = id % gx;
  const int rem0 = id / gx;
  const int bidy = rem0 % gy;
  const int z = rem0 / gy;

  int e = z, koff = 0, KK = p.K;
  if (MODE == 6) { e = z & 3; KK = p.K >> 1; koff = (z >> 2) * KK; }

  const __bf16* Ab = p.A + (long)e * p.sAz + koff;
  const __bf16* Bb = p.Bt + (long)e * p.sBz + koff;
  const float* bias = p.bias + (long)e * p.sBiasZ;
  const float* vec = (MODE == 4 || MODE == 6) ? (p.vec + (long)e * p.sVecZ) : nullptr;

  const int m0 = bidx * BM, n0 = bidy * 128;
  const int tid = threadIdx.x;
  const int w = tid >> 6, lane = tid & 63;
  const int lr = lane & 15, qd = lane >> 4;
  const int wm = (w & 1) * (16 * MF), wn = (w >> 1) * 64;

  // staging map: wave w owns A rows [w*(BM/4), +BM/4) and B rows [w*32, +32);
  // lane l -> row base+(l>>2), col (l&3)*8 bf16 (16B). LDS dest linear.
  const int sra = w * (BM / 4) + (lane >> 2);
  const int srb = w * 32 + (lane >> 2);
  const int sc = (lane & 3) * 8;
  const int lda = p.lda, ldb = p.ldb;
  const __bf16* gA = Ab + (long)(m0 + sra) * lda + sc;
  const __bf16* gB = Bb + (long)(n0 + srb) * ldb + sc;

  f4 acc[MF][4];
#pragma unroll
  for (int i = 0; i < MF; i++)
#pragma unroll
    for (int j = 0; j < 4; j++) acc[i][j] = (f4){0.f, 0.f, 0.f, 0.f};

  const int nk = KK >> 5;

#define STAGE(buf, t)                                                  \
  do {                                                                 \
    const __bf16* a_ = gA + (long)(t) * 32;                            \
    const __bf16* b_ = gB + (long)(t) * 32;                            \
    GLD16(a_, &As[buf][w * (BM / 4)][0]);                              \
    if (AG == 2) GLD16(a_ + 16 * lda, &As[buf][w * (BM / 4) + 16][0]); \
    GLD16(b_,            &Bs[buf][w * 32][0]);                         \
    GLD16(b_ + 16 * ldb, &Bs[buf][w * 32 + 16][0]);                    \
  } while (0)

  // prologue: prefetch depth 2
  STAGE(0, 0);
  if (nk > 1) STAGE(1, 1);

  for (int t = 0; t < nk; ++t) {
    // outstanding at top: tiles t, t+1 (if exists). Wait for tile t only.
    if (t + 1 < nk) {
      if (LPS == 4) asm volatile("s_waitcnt vmcnt(4)" ::: "memory");
      else          asm volatile("s_waitcnt vmcnt(3)" ::: "memory");
    } else {
      asm volatile("s_waitcnt vmcnt(0)" ::: "memory");
    }
    __builtin_amdgcn_s_barrier();          // all waves' tile-t loads landed;
                                           // also: all waves retired slot (t-1)%3 reads
    __builtin_amdgcn_sched_barrier(0);
    if (t + 2 < nk) STAGE((t + 2) % 3, t + 2);  // reuses slot (t-1)%3 — safe per barrier
    __builtin_amdgcn_sched_barrier(0);
    const int cur = t % 3;
    bf16x8 af[MF], bfr[4];
#pragma unroll
    for (int i = 0; i < MF; i++) af[i] = *(const bf16x8*)&As[cur][wm + i*16 + lr][qd*8];
#pragma unroll
    for (int j = 0; j < 4; j++) bfr[j] = *(const bf16x8*)&Bs[cur][wn + j*16 + lr][qd*8];
#pragma unroll
    for (int i = 0; i < MF; i++)
#pragma unroll
      for (int j = 0; j < 4; j++)
        acc[i][j] = __builtin_amdgcn_mfma_f32_16x16x32_bf16(af[i], bfr[j], acc[i][j], 0, 0, 0);
  }
#undef STAGE

  const long cOff = (MODE == 6) ? (long)e * p.sCz : (long)z * p.sCz;
  float* Cf = (float*)p.C + cOff;
  __bf16* Cb = (__bf16*)p.C + cOff;
#pragma unroll
  for (int i = 0; i < MF; i++) {
    const int rbase = m0 + wm + i*16 + qd*4;
#pragma unroll
    for (int j = 0; j < 4; j++) {
      const int col = n0 + wn + j*16 + lr;
      const float bcol = bias[col];
      f4 v = acc[i][j];
#pragma unroll
      for (int r = 0; r < 4; r++) {
        const long o = (long)(rbase + r) * p.ldc + col;
        const float xx = v[r];
        if (MODE == 0) {
          const float y = xx + bcol;
          if (C_BF16) Cb[o] = (__bf16)y; else Cf[o] = y;
        } else if (MODE == 1) {
          const float y = xx + bcol;
          const float g = 0.5f * y * (1.0f + erff(y * 0.70710678118654752f));
          if (C_BF16) Cb[o] = (__bf16)g; else Cf[o] = g;
        } else if (MODE == 4) {
          const float y = vec[(long)(rbase + r) * 4 + z] * xx + bcol;
          if (C_BF16) Cb[o] = (__bf16)y; else Cf[o] = y;
        } else if (MODE == 6) {
          unsafeAtomicAdd(&Cf[o], vec[col] * (xx + (koff == 0 ? bcol : 0.f)));
        }
      }
    }
  }
}

// ---------------------------------------------------------------- MFMA attention
template<int TSQ, int TT>
__global__ __launch_bounds__(256) void attn_mfma_kernel(
    const __bf16* __restrict__ qh, const __bf16* __restrict__ kvh,
    __bf16* __restrict__ att, int qoffG) {
  constexpr int MT = TSQ / 16;        // 4/3/2
  constexpr int NT = TT / 16;         // 20/19/18
  constexpr int NC = (TT + 31) / 32;  // 10/10/9
  constexpr int TC = NC * 32;         // 320/320/288
  constexpr int TPAD = 328;
  __shared__ __bf16 Plds[64 * TPAD];  // 41984 B
  __shared__ unsigned Vt32[64 * 20];  // 5120 B
  __shared__ float redf[64 * 4];      // 1024 B

  const int hh = blockIdx.x;
  const long eb = blockIdx.y;
  const int tid = threadIdx.x;
  const int w = tid >> 6, lane = tid & 63, lr = lane & 15, qd = lane >> 4;

  const __bf16* qb = qh + ((long)eb * 144 + qoffG) * 768 + hh * 64;
  const __bf16* kb = kvh + (long)eb * TT * 1536 + hh * 64;
  const __bf16* vb = kb + 768;

  bf16x8 qf[MT][2];
#pragma unroll
  for (int mt = 0; mt < MT; mt++)
#pragma unroll
    for (int kc = 0; kc < 2; kc++)
      qf[mt][kc] = *(const bf16x8*)(qb + (long)(mt*16 + lr)*768 + kc*32 + qd*8);

  f4 sacc[MT][5];
#pragma unroll
  for (int mt = 0; mt < MT; mt++)
#pragma unroll
    for (int j = 0; j < 5; j++) sacc[mt][j] = (f4){0.f,0.f,0.f,0.f};
#pragma unroll
  for (int j = 0; j < 5; j++) {
    const int jj = w + 4*j;
    if (jj < NT) {
      const int t0 = jj * 16;
      bf16x8 kf0 = *(const bf16x8*)(kb + (long)(t0 + lr)*1536 + qd*8);
      bf16x8 kf1 = *(const bf16x8*)(kb + (long)(t0 + lr)*1536 + 32 + qd*8);
#pragma unroll
      for (int mt = 0; mt < MT; mt++) {
        sacc[mt][j] = __builtin_amdgcn_mfma_f32_16x16x32_bf16(qf[mt][0], kf0, sacc[mt][j], 0,0,0);
        sacc[mt][j] = __builtin_amdgcn_mfma_f32_16x16x32_bf16(qf[mt][1], kf1, sacc[mt][j], 0,0,0);
      }
    }
  }

  float rowmax[MT][4], linv[MT][4], ps[MT][4];
#pragma unroll
  for (int mt = 0; mt < MT; mt++)
#pragma unroll
    for (int r = 0; r < 4; r++) {
      float m = -1e30f;
#pragma unroll
      for (int j = 0; j < 5; j++)
        if (w + 4*j < NT) m = fmaxf(m, sacc[mt][j][r]);
#pragma unroll
      for (int d = 1; d < 16; d <<= 1) m = fmaxf(m, __shfl_xor(m, d));
      rowmax[mt][r] = m;
    }
  if (lr == 0) {
#pragma unroll
    for (int mt = 0; mt < MT; mt++)
#pragma unroll
      for (int r = 0; r < 4; r++)
        redf[(mt*16 + qd*4 + r)*4 + w] = rowmax[mt][r];
  }
  __syncthreads();
#pragma unroll
  for (int mt = 0; mt < MT; mt++)
#pragma unroll
    for (int r = 0; r < 4; r++) {
      f4 v = *(const f4*)&redf[(mt*16 + qd*4 + r)*4];
      rowmax[mt][r] = fmaxf(fmaxf(v[0],v[1]), fmaxf(v[2],v[3])) * 0.125f;
      ps[mt][r] = 0.f;
    }

#pragma unroll
  for (int j = 0; j < 5; j++) {
    const int jj = w + 4*j;
    if (jj < NT) {
#pragma unroll
      for (int mt = 0; mt < MT; mt++)
#pragma unroll
        for (int r = 0; r < 4; r++) {
          float e = __expf(sacc[mt][j][r]*0.125f - rowmax[mt][r]);
          ps[mt][r] += e;
          Plds[(mt*16 + qd*4 + r)*TPAD + jj*16 + lr] = (__bf16)e;
        }
    }
  }
#pragma unroll
  for (int mt = 0; mt < MT; mt++)
#pragma unroll
    for (int r = 0; r < 4; r++) {
      float s = ps[mt][r];
#pragma unroll
      for (int d = 1; d < 16; d <<= 1) s += __shfl_xor(s, d);
      ps[mt][r] = s;
    }
  __syncthreads();
  if (lr == 0) {
#pragma unroll
    for (int mt = 0; mt < MT; mt++)
#pragma unroll
      for (int r = 0; r < 4; r++)
        redf[(mt*16 + qd*4 + r)*4 + w] = ps[mt][r];
  }
  if (TC > TT) {
    for (int idx = tid; idx < 64*(TC-TT); idx += 256) {
      const int rr = idx / (TC-TT), cc = idx % (TC-TT);
      Plds[rr*TPAD + TT + cc] = (__bf16)0.f;
    }
  }
  __syncthreads();
#pragma unroll
  for (int mt = 0; mt < MT; mt++)
#pragma unroll
    for (int r = 0; r < 4; r++) {
      f4 v = *(const f4*)&redf[(mt*16 + qd*4 + r)*4];
      linv[mt][r] = 1.f / (v[0]+v[1]+v[2]+v[3]);
    }

  f4 oacc[MT];
#pragma unroll
  for (int mt = 0; mt < MT; mt++) oacc[mt] = (f4){0.f,0.f,0.f,0.f};
  const int n0 = w * 16;
  for (int c = 0; c < NC; c++) {
    {
      const int tp = tid & 15, dq = tid >> 4;
      const int t0v = c*32 + tp*2;
      u16x4 v0 = (u16x4){0,0,0,0}, v1 = (u16x4){0,0,0,0};
      if (t0v < TT)     v0 = *(const u16x4*)(vb + (long)t0v*1536 + dq*4);
      if (t0v + 1 < TT) v1 = *(const u16x4*)(vb + (long)(t0v+1)*1536 + dq*4);
#pragma unroll
      for (int i = 0; i < 4; i++)
        Vt32[(dq*4 + i)*20 + tp] = ((unsigned)v1[i] << 16) | (unsigned)v0[i];
    }
    __syncthreads();
    bf16x8 vf = *(const bf16x8*)&Vt32[(n0 + lr)*20 + qd*4];
#pragma unroll
    for (int mt = 0; mt < MT; mt++) {
      bf16x8 pf = *(const bf16x8*)&Plds[(mt*16 + lr)*TPAD + c*32 + qd*8];
      oacc[mt] = __builtin_amdgcn_mfma_f32_16x16x32_bf16(pf, vf, oacc[mt], 0,0,0);
    }
    __syncthreads();
  }

  __bf16* ob = att + ((long)eb*144 + qoffG)*768 + hh*64 + n0 + lr;
#pragma unroll
  for (int mt = 0; mt < MT; mt++)
#pragma unroll
    for (int r = 0; r < 4; r++) {
      const int row = mt*16 + qd*4 + r;
      ob[(long)row * 768] = (__bf16)(oacc[mt][r] * linv[mt][r]);
    }
}

// ---------------------------------------------------------------- RMSNorm
__global__ __launch_bounds__(256) void rmsnorm_kernel(
    const float* __restrict__ in, const float* __restrict__ w,
    const float* __restrict__ g, float* __restrict__ out) {
  const long r = blockIdx.x;
  const int tid = threadIdx.x;
  const float* src = in + r*4096;
  f4 vv[4]; float s2 = 0.f;
#pragma unroll
  for (int i = 0; i < 4; i++) {
    vv[i] = *(const f4*)(src + i*1024 + tid*4);
    s2 += vv[i][0]*vv[i][0] + vv[i][1]*vv[i][1] + vv[i][2]*vv[i][2] + vv[i][3]*vv[i][3];
  }
#pragma unroll
  for (int off = 32; off; off >>= 1) s2 += __shfl_down(s2, off);
  __shared__ float red[4];
  if ((tid & 63) == 0) red[tid >> 6] = s2;
  __syncthreads();
  const float ms = (red[0]+red[1]+red[2]+red[3]) * (1.f/4096.f);
  const float scl = rsqrtf(ms + 1e-6f);
#pragma unroll
  for (int i = 0; i < 4; i++) {
    const int o = i*1024 + tid*4;
    f4 wv = *(const f4*)(w + o);
    f4 gv = *(const f4*)(g + o);
    f4 res = vv[i] * scl * wv * gv;
    *(f4*)(out + r*4096 + o) = res;
  }
}

// ================================================================ launch
extern "C" void kernel_launch(void* const* d_in, const int* in_sizes, int n_in,
                              void* d_out, int out_size, void* d_ws, size_t ws_size,
                              hipStream_t stream) {
  const float* x          = (const float*)d_in[0];
  const float* gate_ln_w  = (const float*)d_in[1];
  const float* gate_ln_b  = (const float*)d_in[2];
  const float* gate_w     = (const float*)d_in[3];
  const float* gate_b     = (const float*)d_in[4];
  const float* exp_in_w   = (const float*)d_in[5];
  const float* exp_in_b   = (const float*)d_in[6];
  const float* exp_query  = (const float*)d_in[7];
  const float* ln1_w      = (const float*)d_in[8];
  const float* ln1_b      = (const float*)d_in[9];
  const float* ln1kv_w    = (const float*)d_in[10];
  const float* ln1kv_b    = (const float*)d_in[11];
  const float* ln2_w      = (const float*)d_in[12];
  const float* ln2_b      = (const float*)d_in[13];
  const float* attn_in_w  = (const float*)d_in[14];
  const float* attn_in_b  = (const float*)d_in[15];
  const float* attn_out_w = (const float*)d_in[16];
  const float* attn_out_b = (const float*)d_in[17];
  const float* ls1        = (const float*)d_in[18];
  const float* ls2        = (const float*)d_in[19];
  const float* fc_w       = (const float*)d_in[20];
  const float* fc_b       = (const float*)d_in[21];
  const float* proj_w     = (const float*)d_in[22];
  const float* proj_b     = (const float*)d_in[23];
  const float* out_w      = (const float*)d_in[24];
  const float* out_b      = (const float*)d_in[25];
  const float* rms_w      = (const float*)d_in[26];
  const float* out_gain   = (const float*)d_in[27];
  float* out = (float*)d_out;

  // ---- workspace layout (byte offsets), total 132,218,880 B (unchanged)
  char* W = (char*)d_ws;
  float*   gw     = (float*)(W + 0);             // 98,304 B; dead after expert gemm
  float*   bsum   = (float*)(W + 0);             // alias gw (out-proj bias sum, 16 KB)
  float*   t      = (float*)(W + 98304);
  __bf16*  qn     = (__bf16*)(W + 14254080);     // alias att; tb_cat at the end
  __bf16*  tbcat  = (__bf16*)(W + 14254080);     // [1152][3072] bf16 = 7,077,888 B
  __bf16*  qh     = (__bf16*)(W + 21331968);
  __bf16*  kvn    = (__bf16*)(W + 28409856);
  __bf16*  kvh    = (__bf16*)(W + 44138496);     // alias mid, outw_cat
  __bf16*  mid    = (__bf16*)(W + 44138496);
  __bf16*  outwc  = (__bf16*)(W + 44138496);     // [4096][3072] bf16 = 25.2 MB <= 31.4 MB
  __bf16*  h      = (__bf16*)(W + 75595776);
  float*   mixed  = (float*)(W + 75595776);      // alias h (h dead by then)
  __bf16*  wbuf   = (__bf16*)(W + 113344512);    // 6.29 MB weights
  __bf16*  xb     = (__bf16*)(W + 119635968);    // x in bf16, 12.58 MB (tail)
  const size_t NEED = 132218880ull;
  if (ws_size < NEED) return;

  // ---- gating (writes xb as a side effect)
  gate_kernel<<<6144, 256, 0, stream>>>(x, gate_ln_w, gate_ln_b, gate_w, gate_b, gw, xb);

  // ---- expert input proj: h[e] = gate_e * (x @ exp_in_w[e]) + bias
  transpose_cvt<<<dim3(24,32,4), 256, 0, stream>>>(exp_in_w, wbuf, 768, 1024, 786432, 786432);
  { GemmP p{ xb, 0, 1024, wbuf, 786432, 1024, h, 4718592, 768,
             exp_in_b, 768, gw, 0, 1024 };
    gemm128<4,true,128><<<dim3(48,6,4), 256, 0, stream>>>(p); }
  init_t_kernel<<<3456, 256, 0, stream>>>(exp_query, t);

  const int ST[3]  = {320, 304, 288};
  const int SQ[3]  = {64, 48, 32};
  const int QO[3]  = {0, 64, 112};
  const int LO[3]  = {0, 256, 512};

  for (int li = 0; li < 2; li++) {
    transpose_cvt<<<dim3(72,24,4), 256, 0, stream>>>(
        attn_in_w + (long)li*768*2304, wbuf, 2304, 768, 3538944, 1769472);
    ln_rows_kernel<<<4608, 256, 0, stream>>>(t, qn, ln1_w + li*768, ln1_b + li*768);
    { GemmP p{ qn, 884736, 768, wbuf, 1769472, 768, qh, 884736, 768,
               attn_in_b + li*2304, 4608, nullptr, 0, 768 };
      gemm128<0,true,64><<<dim3(18,6,4), 256, 0, stream>>>(p); }
    for (int s = 0; s < 3; s++) {
      const int T = ST[s];
      ln_kv_kernel<<<32*T, 256, 0, stream>>>(h, exp_query, kvn,
          ln1kv_w + li*768, ln1kv_b + li*768, T, SQ[s], QO[s], LO[s]);
      { GemmP p{ kvn, (long)8*T*768, 768, wbuf + 768*768, 1769472, 768,
                 kvh, (long)8*T*1536, 1536,
                 attn_in_b + li*2304 + 768, 4608, nullptr, 0, 768 };
        gemm128<0,true,128><<<dim3(8*T/128,12,4), 256, 0, stream>>>(p); }
      if (s == 0)
        attn_mfma_kernel<64,320><<<dim3(12,32), 256, 0, stream>>>(qh, kvh, qn, QO[s]);
      else if (s == 1)
        attn_mfma_kernel<48,304><<<dim3(12,32), 256, 0, stream>>>(qh, kvh, qn, QO[s]);
      else
        attn_mfma_kernel<32,288><<<dim3(12,32), 256, 0, stream>>>(qh, kvh, qn, QO[s]);
    }
    // attn out proj with split-K=2 (z = half*4 + e), atomic += into t
    transpose_cvt<<<dim3(24,24,4), 256, 0, stream>>>(
        attn_out_w + (long)li*589824, wbuf, 768, 768, 1179648, 589824);
    { GemmP p{ qn /*att*/, 884736, 768, wbuf, 589824, 768, t, 884736, 768,
               attn_out_b + li*768, 1536, ls1 + li*768, 1536, 768 };
      gemm128<6,false,64><<<dim3(18,6,8), 256, 0, stream>>>(p); }
    ln_rows_kernel<<<4608, 256, 0, stream>>>(t, qn, ln2_w + li*768, ln2_b + li*768);
    transpose_cvt<<<dim3(96,24,4), 256, 0, stream>>>(
        fc_w + (long)li*768*3072, wbuf, 3072, 768, 4718592, 2359296);
    { GemmP p{ qn, 884736, 768, wbuf, 2359296, 768, mid, 3538944, 3072,
               fc_b + li*3072, 6144, nullptr, 0, 768 };
      gemm128<1,true,128><<<dim3(9,24,4), 256, 0, stream>>>(p); }
    transpose_cvt<<<dim3(24,96,4), 256, 0, stream>>>(
        proj_w + (long)li*3072*768, wbuf, 768, 3072, 4718592, 2359296);
    { GemmP p{ mid, 3538944, 3072, wbuf, 2359296, 3072, t, 884736, 768,
               proj_b + li*768, 1536, ls2 + li*768, 1536, 3072 };
      gemm128<6,false,64><<<dim3(18,6,8), 256, 0, stream>>>(p); }
  }

  // ---- final out proj as ONE GEMM with K concatenated over experts (K=3072)
  cvt_tcat_kernel<<<3456, 256, 0, stream>>>(t, tbcat);
  bias_sum_kernel<<<16, 256, 0, stream>>>(out_b, bsum);
  transpose_cvt<<<dim3(128,24,4), 256, 0, stream>>>(out_w, outwc, 4096, 3072, 3145728, 768);
  { GemmP p{ tbcat, 0, 3072, outwc, 0, 3072, mixed, 0, 4096,
             bsum, 0, nullptr, 0, 3072 };
    gemm128<0,false,64><<<dim3(18,32,1), 256, 0, stream>>>(p); }
  rmsnorm_kernel<<<1152, 256, 0, stream>>>(mixed, rms_w, out_gain, out);
}